// Round 7
// baseline (495.432 us; speedup 1.0000x reference)
//
#include <hip/hip_runtime.h>
#include <hip/hip_bf16.h>

typedef __hip_bfloat16 bf16;
typedef __attribute__((ext_vector_type(8))) __bf16 bf16x8;
typedef __attribute__((ext_vector_type(4))) float  f32x4;

#define HW   65536
#define WID  256
#define CC   96
#define NB   4
static const size_t S_ELEMS = (size_t)NB * CC * HW;  // 25,165,824 elements

__device__ __forceinline__ float lo2f(unsigned u) { unsigned x = u << 16;        return __builtin_bit_cast(float, x); }
__device__ __forceinline__ float hi2f(unsigned u) { unsigned x = u & 0xffff0000u; return __builtin_bit_cast(float, x); }
__device__ __forceinline__ unsigned short f2bu(float f) {
    return __builtin_bit_cast(unsigned short, __float2bfloat16(f));
}

// exact-GELU via Abramowitz-Stegun 7.1.26 erf (|err| < 1.5e-7)
__device__ __forceinline__ float gelu_erf(float v) {
    float z  = fabsf(v) * 0.70710678118654752f;
    float t  = __builtin_amdgcn_rcpf(1.f + 0.3275911f * z);
    float poly = t * (0.254829592f + t * (-0.284496736f + t * (1.421413741f
               + t * (-1.453152027f + t * 1.061405429f))));
    float erfz = 1.f - poly * __expf(-z * z);
    float erfv = copysignf(erfz, v);
    return 0.5f * v * (1.f + erfv);
}

// ---------------- Kernel 1: LayerNorm over channel dim of NCHW ----------------
__global__ __launch_bounds__(256) void ln_kernel(
    const float* __restrict__ x, const float* __restrict__ lw,
    const float* __restrict__ lb, bf16* __restrict__ y)
{
    int t  = blockIdx.x * 256 + threadIdx.x;   // [0, 131072)
    int b  = t >> 15;
    int hw = (t & 32767) * 2;
    size_t base = (size_t)b * CC * HW + hw;

    float s0 = 0.f, s1 = 0.f, q0 = 0.f, q1 = 0.f;
    for (int c = 0; c < CC; ++c) {
        float2 v = *reinterpret_cast<const float2*>(&x[base + (size_t)c * HW]);
        s0 += v.x; s1 += v.y; q0 += v.x * v.x; q1 += v.y * v.y;
    }
    float mu0 = s0 * (1.f / 96.f), mu1 = s1 * (1.f / 96.f);
    float rs0 = rsqrtf(q0 * (1.f / 96.f) - mu0 * mu0 + 1e-6f);
    float rs1 = rsqrtf(q1 * (1.f / 96.f) - mu1 * mu1 + 1e-6f);

    for (int c = 0; c < CC; ++c) {
        float2 v = *reinterpret_cast<const float2*>(&x[base + (size_t)c * HW]);
        float g = lw[c], be = lb[c];
        bf16 o[2];
        o[0] = __float2bfloat16((v.x - mu0) * rs0 * g + be);
        o[1] = __float2bfloat16((v.y - mu1) * rs1 * g + be);
        *reinterpret_cast<uint*>(&y[base + (size_t)c * HW]) = *reinterpret_cast<uint*>(o);
    }
}

// ---------------- conv1x1 via MFMA 16x16x32 bf16 (k2 only) -------------------
__device__ __forceinline__ int swzo(int row, int col, int width) {
    return (row * width + col) ^ ((((row & 7) ^ ((row >> 3) & 7)) << 3));
}

template <typename TI, typename TOT, int CIN, int COUT, bool GELU, bool HASRES>
__global__ __launch_bounds__(256) void conv1x1_mfma(
    const TI* __restrict__ in, const float* __restrict__ wgt,
    const float* __restrict__ bias, const float* __restrict__ resid,
    TOT* __restrict__ out)
{
    constexpr int KSPLIT = CIN / 96;
    constexpr int OSPLIT = COUT / 96;
    constexpr int MT     = 6;
    static_assert(CIN == KSPLIT * 96 && COUT == OSPLIT * 96, "96-multiples only");

    __shared__ unsigned short s_w[96 * 96];
    __shared__ unsigned short s_x[128 * 96];
    __shared__ float          s_b[COUT];

    const int tid  = threadIdx.x;
    const int lane = tid & 63;
    const int wave = tid >> 6;
    const int q    = lane >> 4;
    const int n    = lane & 15;

    const int pos0 = blockIdx.x * 128;
    const int b    = pos0 >> 16;
    const int hw0  = pos0 & 65535;

    for (int k = tid; k < COUT; k += 256) s_b[k] = bias[k];

    const TI* inb = in + (size_t)b * CIN * HW;
    const int pl0 = wave * 32 + n;
    const int pl1 = pl0 + 16;

#pragma unroll
    for (int os = 0; os < OSPLIT; ++os) {
        f32x4 acc[MT][2];
#pragma unroll
        for (int mt = 0; mt < MT; ++mt) {
            acc[mt][0] = {0.f, 0.f, 0.f, 0.f};
            acc[mt][1] = {0.f, 0.f, 0.f, 0.f};
        }

#pragma unroll
        for (int ks = 0; ks < KSPLIT; ++ks) {
            for (int k = tid; k < 96 * 24; k += 256) {
                int o = k / 24, c4 = (k - o * 24) * 4;
                float4 w4 = *reinterpret_cast<const float4*>(
                    &wgt[(size_t)(os * 96 + o) * CIN + ks * 96 + c4]);
                ushort4 pk = make_ushort4(f2bu(w4.x), f2bu(w4.y), f2bu(w4.z), f2bu(w4.w));
                *reinterpret_cast<ushort4*>(&s_w[swzo(o, c4, 96)]) = pk;
            }
            if (KSPLIT > 1 || os == 0) {
                for (int idx = tid; idx < 48 * 16; idx += 256) {
                    const int cp = idx >> 4;
                    const int pb = idx & 15;
                    const TI* gp = inb + (size_t)(ks * 96 + 2 * cp) * HW + hw0 + pb * 8;
                    unsigned short ua[8], ub[8];
                    if constexpr (__is_same(TI, float)) {
                        float4 a0 = *reinterpret_cast<const float4*>(gp);
                        float4 a1 = *reinterpret_cast<const float4*>(gp + 4);
                        float4 b0 = *reinterpret_cast<const float4*>(gp + HW);
                        float4 b1 = *reinterpret_cast<const float4*>(gp + HW + 4);
                        ua[0]=f2bu(a0.x); ua[1]=f2bu(a0.y); ua[2]=f2bu(a0.z); ua[3]=f2bu(a0.w);
                        ua[4]=f2bu(a1.x); ua[5]=f2bu(a1.y); ua[6]=f2bu(a1.z); ua[7]=f2bu(a1.w);
                        ub[0]=f2bu(b0.x); ub[1]=f2bu(b0.y); ub[2]=f2bu(b0.z); ub[3]=f2bu(b0.w);
                        ub[4]=f2bu(b1.x); ub[5]=f2bu(b1.y); ub[6]=f2bu(b1.z); ub[7]=f2bu(b1.w);
                    } else {
                        *reinterpret_cast<uint4*>(ua) = *reinterpret_cast<const uint4*>(gp);
                        *reinterpret_cast<uint4*>(ub) = *reinterpret_cast<const uint4*>(gp + HW);
                    }
#pragma unroll
                    for (int i = 0; i < 8; ++i) {
                        uint d = (uint)ua[i] | ((uint)ub[i] << 16);
                        *reinterpret_cast<uint*>(&s_x[swzo(pb * 8 + i, 2 * cp, 96)]) = d;
                    }
                }
            }
            __syncthreads();

#pragma unroll
            for (int kt = 0; kt < 3; ++kt) {
                const int col = kt * 32 + q * 8;
                union { unsigned short u[8]; bf16x8 v; } bf0, bf1;
                *reinterpret_cast<uint4*>(bf0.u) =
                    *reinterpret_cast<const uint4*>(&s_x[swzo(pl0, col, 96)]);
                *reinterpret_cast<uint4*>(bf1.u) =
                    *reinterpret_cast<const uint4*>(&s_x[swzo(pl1, col, 96)]);
#pragma unroll
                for (int mt = 0; mt < MT; ++mt) {
                    union { unsigned short u[8]; bf16x8 v; } fa;
                    *reinterpret_cast<uint4*>(fa.u) =
                        *reinterpret_cast<const uint4*>(&s_w[swzo(mt * 16 + n, col, 96)]);
                    acc[mt][0] = __builtin_amdgcn_mfma_f32_16x16x32_bf16(fa.v, bf0.v, acc[mt][0], 0, 0, 0);
                    acc[mt][1] = __builtin_amdgcn_mfma_f32_16x16x32_bf16(fa.v, bf1.v, acc[mt][1], 0, 0, 0);
                }
            }
            if (os + 1 < OSPLIT || ks + 1 < KSPLIT)
                __syncthreads();
        }

        const int p0 = hw0 + pl0;
        const int p1 = hw0 + pl1;
        const size_t obase = (size_t)b * COUT * HW;
#pragma unroll
        for (int mt = 0; mt < MT; ++mt) {
#pragma unroll
            for (int nt = 0; nt < 2; ++nt) {
                const int p = (nt == 0) ? p0 : p1;
#pragma unroll
                for (int r = 0; r < 4; ++r) {
                    const int o = os * 96 + mt * 16 + q * 4 + r;
                    float v = acc[mt][nt][r] + s_b[o];
                    if constexpr (GELU) v = gelu_erf(v);
                    const size_t idx = obase + (size_t)o * HW + p;
                    if constexpr (HASRES) v += resid[idx];
                    if constexpr (__is_same(TOT, float)) out[idx] = v;
                    else                                 out[idx] = __float2bfloat16(v);
                }
            }
        }
    }
}

// ---------------- Fused FFN: out = x1 + ffn2(gelu(ffn1(x1))), x1 = x+proj(xa)
// One block = 128 positions; x1 kept in fp32 REGISTERS (never touches memory);
// h staged in LDS halves (pitch 104 elems = 52 dwords === 20 mod 32 -> row
// banks 2-way = free for b128 reads, and 8-elem-multiple so b64/b128 aligned).
// Single 96x96 W-slice LDS buffer cycled: proj, w1h0, w1h1, w2k0, w2k1.
// xa tile and h share one LDS region (xa dead after GEMM-proj). 73.2 KB total
// -> 2 blocks/CU. No in-place RMW: d_out written exactly once.
__global__ __launch_bounds__(256) void ffn_fused(
    const bf16* __restrict__ xa, const float* __restrict__ x,
    const float* __restrict__ pw, const float* __restrict__ pb,
    const float* __restrict__ w1, const float* __restrict__ b1,
    const float* __restrict__ w2, const float* __restrict__ b2,
    float* __restrict__ out)
{
    constexpr int HP = 104;                       // x1/h tile pitch (elems)
    __shared__ unsigned short s_w[96 * 96];       // 18,432 B  current W slice
    __shared__ unsigned short s_x1[128 * HP];     // 26,624 B  x1 bf16
    __shared__ unsigned short s_hx[128 * HP];     // 26,624 B  xa (swz96) then h
    __shared__ float          s_bias[384];        // pb[96] | b1[192] | b2[96]

    const int tid  = threadIdx.x;
    const int lane = tid & 63;
    const int wave = tid >> 6;
    const int q    = lane >> 4;
    const int n    = lane & 15;

    const int pos0 = blockIdx.x * 128;
    const int b    = pos0 >> 16;
    const int hw0  = pos0 & 65535;
    const int pl0  = wave * 32 + n;
    const int pl1  = pl0 + 16;

    auto stage_w = [&](const float* W, int row0, int col0, int rstride) {
        for (int k = tid; k < 96 * 24; k += 256) {
            int o = k / 24, c4 = (k - o * 24) * 4;
            float4 w4 = *reinterpret_cast<const float4*>(
                &W[(size_t)(row0 + o) * rstride + col0 + c4]);
            ushort4 pk = make_ushort4(f2bu(w4.x), f2bu(w4.y), f2bu(w4.z), f2bu(w4.w));
            *reinterpret_cast<ushort4*>(&s_w[swzo(o, c4, 96)]) = pk;
        }
    };
    auto gemm_swz = [&](f32x4 (&acc)[6][2]) {     // B = s_hx, swizzled width 96
#pragma unroll
        for (int kt = 0; kt < 3; ++kt) {
            const int col = kt * 32 + q * 8;
            union { unsigned short u[8]; bf16x8 v; } bf0, bf1;
            *reinterpret_cast<uint4*>(bf0.u) =
                *reinterpret_cast<const uint4*>(&s_hx[swzo(pl0, col, 96)]);
            *reinterpret_cast<uint4*>(bf1.u) =
                *reinterpret_cast<const uint4*>(&s_hx[swzo(pl1, col, 96)]);
#pragma unroll
            for (int mt = 0; mt < 6; ++mt) {
                union { unsigned short u[8]; bf16x8 v; } fa;
                *reinterpret_cast<uint4*>(fa.u) =
                    *reinterpret_cast<const uint4*>(&s_w[swzo(mt * 16 + n, col, 96)]);
                acc[mt][0] = __builtin_amdgcn_mfma_f32_16x16x32_bf16(fa.v, bf0.v, acc[mt][0], 0, 0, 0);
                acc[mt][1] = __builtin_amdgcn_mfma_f32_16x16x32_bf16(fa.v, bf1.v, acc[mt][1], 0, 0, 0);
            }
        }
    };
    auto gemm_lin = [&](const unsigned short* B, f32x4 (&acc)[6][2]) {  // pitch HP
#pragma unroll
        for (int kt = 0; kt < 3; ++kt) {
            const int col = kt * 32 + q * 8;
            union { unsigned short u[8]; bf16x8 v; } bf0, bf1;
            *reinterpret_cast<uint4*>(bf0.u) =
                *reinterpret_cast<const uint4*>(&B[pl0 * HP + col]);
            *reinterpret_cast<uint4*>(bf1.u) =
                *reinterpret_cast<const uint4*>(&B[pl1 * HP + col]);
#pragma unroll
            for (int mt = 0; mt < 6; ++mt) {
                union { unsigned short u[8]; bf16x8 v; } fa;
                *reinterpret_cast<uint4*>(fa.u) =
                    *reinterpret_cast<const uint4*>(&s_w[swzo(mt * 16 + n, col, 96)]);
                acc[mt][0] = __builtin_amdgcn_mfma_f32_16x16x32_bf16(fa.v, bf0.v, acc[mt][0], 0, 0, 0);
                acc[mt][1] = __builtin_amdgcn_mfma_f32_16x16x32_bf16(fa.v, bf1.v, acc[mt][1], 0, 0, 0);
            }
        }
    };
    auto st4 = [&](unsigned short* dst, int elem, float v0, float v1, float v2, float v3) {
        union { unsigned short u[4]; uint2 d; } t;
        t.u[0] = f2bu(v0); t.u[1] = f2bu(v1); t.u[2] = f2bu(v2); t.u[3] = f2bu(v3);
        *reinterpret_cast<uint2*>(&dst[elem]) = t.d;      // b64, aligned (HP%8==0)
    };

    // ---------- S0: xa -> s_hx (swizzled 96), proj W -> s_w, biases
    {
        const bf16* inb = xa + (size_t)b * 96 * HW;
        for (int idx = tid; idx < 48 * 16; idx += 256) {
            const int cp = idx >> 4, pbk = idx & 15;
            const bf16* gp = inb + (size_t)(2 * cp) * HW + hw0 + pbk * 8;
            unsigned short ua[8], ub[8];
            *reinterpret_cast<uint4*>(ua) = *reinterpret_cast<const uint4*>(gp);
            *reinterpret_cast<uint4*>(ub) = *reinterpret_cast<const uint4*>(gp + HW);
#pragma unroll
            for (int i = 0; i < 8; ++i) {
                uint d = (uint)ua[i] | ((uint)ub[i] << 16);
                *reinterpret_cast<uint*>(&s_hx[swzo(pbk * 8 + i, 2 * cp, 96)]) = d;
            }
        }
    }
    stage_w(pw, 0, 0, 96);
    if (tid < 96)  s_bias[tid]       = pb[tid];
    if (tid < 192) s_bias[96 + tid]  = b1[tid];
    if (tid < 96)  s_bias[288 + tid] = b2[tid];
    __syncthreads();

    // ---------- G-proj (x resid loads issued first; hide under MFMAs)
    float xr[6][2][4];
    {
        const size_t xbase = (size_t)b * 96 * HW;
#pragma unroll
        for (int mt = 0; mt < 6; ++mt)
#pragma unroll
            for (int nt = 0; nt < 2; ++nt) {
                const int p = hw0 + (nt ? pl1 : pl0);
#pragma unroll
                for (int r = 0; r < 4; ++r)
                    xr[mt][nt][r] = x[xbase + (size_t)(mt * 16 + q * 4 + r) * HW + p];
            }
    }
    f32x4 accp[6][2];
#pragma unroll
    for (int mt = 0; mt < 6; ++mt) { accp[mt][0] = {0,0,0,0}; accp[mt][1] = {0,0,0,0}; }
    gemm_swz(accp);

    float x1f[6][2][4];
#pragma unroll
    for (int mt = 0; mt < 6; ++mt)
#pragma unroll
        for (int nt = 0; nt < 2; ++nt) {
            const int p = nt ? pl1 : pl0;
#pragma unroll
            for (int r = 0; r < 4; ++r)
                x1f[mt][nt][r] = accp[mt][nt][r] + s_bias[mt * 16 + q * 4 + r] + xr[mt][nt][r];
            st4(s_x1, p * HP + mt * 16 + q * 4,
                x1f[mt][nt][0], x1f[mt][nt][1], x1f[mt][nt][2], x1f[mt][nt][3]);
        }
    __syncthreads();                       // s_w free; s_x1 visible

    // ---------- GEMM1 half0 -> h0 in s_hx
    stage_w(w1, 0, 0, 96);
    __syncthreads();
    f32x4 acc1[6][2];
#pragma unroll
    for (int mt = 0; mt < 6; ++mt) { acc1[mt][0] = {0,0,0,0}; acc1[mt][1] = {0,0,0,0}; }
    gemm_lin(s_x1, acc1);
#pragma unroll
    for (int mt = 0; mt < 6; ++mt)
#pragma unroll
        for (int nt = 0; nt < 2; ++nt) {
            const int p = nt ? pl1 : pl0;
            float v0 = gelu_erf(acc1[mt][nt][0] + s_bias[96 + mt * 16 + q * 4 + 0]);
            float v1 = gelu_erf(acc1[mt][nt][1] + s_bias[96 + mt * 16 + q * 4 + 1]);
            float v2 = gelu_erf(acc1[mt][nt][2] + s_bias[96 + mt * 16 + q * 4 + 2]);
            float v3 = gelu_erf(acc1[mt][nt][3] + s_bias[96 + mt * 16 + q * 4 + 3]);
            st4(s_hx, p * HP + mt * 16 + q * 4, v0, v1, v2, v3);
        }
    __syncthreads();                       // s_w free; h0 visible

    // ---------- GEMM1 half1 (kept in regs until h0 consumed)
    stage_w(w1, 96, 0, 96);
    __syncthreads();
    f32x4 acc1b[6][2];
#pragma unroll
    for (int mt = 0; mt < 6; ++mt) { acc1b[mt][0] = {0,0,0,0}; acc1b[mt][1] = {0,0,0,0}; }
    gemm_lin(s_x1, acc1b);
    __syncthreads();                       // s_w free

    // ---------- GEMM2 k-half0 (consumes h0)
    stage_w(w2, 0, 0, 192);
    __syncthreads();
    f32x4 acc2[6][2];
#pragma unroll
    for (int mt = 0; mt < 6; ++mt) { acc2[mt][0] = {0,0,0,0}; acc2[mt][1] = {0,0,0,0}; }
    gemm_lin(s_hx, acc2);
    __syncthreads();                       // h0 reads + s_w reads done

    // ---------- stage W2k1 + write h1, then GEMM2 k-half1
    stage_w(w2, 0, 96, 192);
#pragma unroll
    for (int mt = 0; mt < 6; ++mt)
#pragma unroll
        for (int nt = 0; nt < 2; ++nt) {
            const int p = nt ? pl1 : pl0;
            float v0 = gelu_erf(acc1b[mt][nt][0] + s_bias[192 + mt * 16 + q * 4 + 0]);
            float v1 = gelu_erf(acc1b[mt][nt][1] + s_bias[192 + mt * 16 + q * 4 + 1]);
            float v2 = gelu_erf(acc1b[mt][nt][2] + s_bias[192 + mt * 16 + q * 4 + 2]);
            float v3 = gelu_erf(acc1b[mt][nt][3] + s_bias[192 + mt * 16 + q * 4 + 3]);
            st4(s_hx, p * HP + mt * 16 + q * 4, v0, v1, v2, v3);
        }
    __syncthreads();
    gemm_lin(s_hx, acc2);

    // ---------- epilogue: out = x1 + ffn2 + b2  (single write, no RMW)
    const size_t obase = (size_t)b * 96 * HW;
#pragma unroll
    for (int mt = 0; mt < 6; ++mt)
#pragma unroll
        for (int nt = 0; nt < 2; ++nt) {
            const int p = hw0 + (nt ? pl1 : pl0);
#pragma unroll
            for (int r = 0; r < 4; ++r) {
                const int o = mt * 16 + q * 4 + r;
                out[obase + (size_t)o * HW + p] =
                    x1f[mt][nt][r] + acc2[mt][nt][r] + s_bias[288 + o];
            }
        }
}

// ---------------- Kernel 3: experts, TRANSPOSED LDS stencil ----------------
#define XR     20
#define XPITCH 22      // 11 dwords (odd)
#define TPITCH 10      // 5 dwords (odd)
#define XCOLS  268
#define TCOLS  258

__global__ __launch_bounds__(256) void experts_kernel(
    const bf16* __restrict__ xn, const bf16* __restrict__ t0,
    const float* __restrict__ w0, const float* __restrict__ b0,
    const float* __restrict__ w1, const float* __restrict__ b1,
    const float* __restrict__ w2, const float* __restrict__ b2,
    const float* __restrict__ sw, const float* __restrict__ prompt,
    bf16* __restrict__ xa)
{
    __shared__ alignas(16) unsigned short sxT[XCOLS * XPITCH];
    __shared__ alignas(16) unsigned short stT[TCOLS * TPITCH];

    const int tid  = threadIdx.x;
    const int lane = tid & 63;
    const int wave = tid >> 6;
    const int bid = blockIdx.x;
    const int h0  = (bid & 31) * 8;
    const int bc  = bid >> 5;
    const int b   = bc / 96;
    const int c   = bc - b * 96;
    const size_t pbase = (size_t)bc * HW;

    const bf16* xp = xn + pbase;
    const bf16* tp = t0 + pbase;
    uint* sx32 = reinterpret_cast<uint*>(sxT);
    uint* st32 = reinterpret_cast<uint*>(stT);

    if (tid < 132) {
        int cc = tid / 11, d = tid - cc * 11;
        int col = (cc < 6) ? cc : 256 + cc;
        sx32[col * 11 + d] = 0u;
    } else if (tid < 142) {
        int i = tid - 132;
        int col = (i < 5) ? 0 : 257;
        int d   = (i < 5) ? i : i - 5;
        st32[col * 5 + d] = 0u;
    }

    {
        const int rp = (lane >> 2) & 7;
        const int ch = 8 * wave + (lane & 3) + ((lane >> 5) << 2);
        const int gh0 = h0 - 6 + 2 * rp, gh1 = gh0 + 1;
        union { uint4 q; unsigned short u[8]; } a, bb;
        a.q  = ((unsigned)gh0 < 256u) ? *reinterpret_cast<const uint4*>(xp + gh0 * WID + ch * 8)
                                      : make_uint4(0u, 0u, 0u, 0u);
        bb.q = ((unsigned)gh1 < 256u) ? *reinterpret_cast<const uint4*>(xp + gh1 * WID + ch * 8)
                                      : make_uint4(0u, 0u, 0u, 0u);
        const int base = 11 * (6 + 8 * ch) + rp;
#pragma unroll
        for (int j = 0; j < 8; ++j)
            sx32[base + 11 * j] = (uint)a.u[j] | ((uint)bb.u[j] << 16);
    }
    if (wave == 2) {
        const int rp = 8 + ((lane >> 2) & 1);
        const int ch = (lane & 3) + (((lane >> 3) & 7) << 2);
        const int gh0 = h0 - 6 + 2 * rp, gh1 = gh0 + 1;
        union { uint4 q; unsigned short u[8]; } a, bb;
        a.q  = ((unsigned)gh0 < 256u) ? *reinterpret_cast<const uint4*>(xp + gh0 * WID + ch * 8)
                                      : make_uint4(0u, 0u, 0u, 0u);
        bb.q = ((unsigned)gh1 < 256u) ? *reinterpret_cast<const uint4*>(xp + gh1 * WID + ch * 8)
                                      : make_uint4(0u, 0u, 0u, 0u);
        const int base = 11 * (6 + 8 * ch) + rp;
#pragma unroll
        for (int j = 0; j < 8; ++j)
            sx32[base + 11 * j] = (uint)a.u[j] | ((uint)bb.u[j] << 16);
    }
    if (wave < 2) {
        const int rp = (lane >> 3) & 3;
        const int ch = 16 * wave + (lane & 7) + ((lane >> 5) << 3);
        const int gh0 = h0 - 1 + 2 * rp, gh1 = gh0 + 1;
        union { uint4 q; unsigned short u[8]; } a, bb;
        a.q  = ((unsigned)gh0 < 256u) ? *reinterpret_cast<const uint4*>(tp + gh0 * WID + ch * 8)
                                      : make_uint4(0u, 0u, 0u, 0u);
        bb.q = ((unsigned)gh1 < 256u) ? *reinterpret_cast<const uint4*>(tp + gh1 * WID + ch * 8)
                                      : make_uint4(0u, 0u, 0u, 0u);
        const int base = 5 * (1 + 8 * ch) + rp;
#pragma unroll
        for (int j = 0; j < 8; ++j)
            st32[base + 5 * j] = (uint)a.u[j] | ((uint)bb.u[j] << 16);
    }
    if (wave == 3 && lane < 32) {
        const int rp = 4;
        const int ch = lane;
        const int gh0 = h0 - 1 + 2 * rp, gh1 = gh0 + 1;
        union { uint4 q; unsigned short u[8]; } a, bb;
        a.q  = ((unsigned)gh0 < 256u) ? *reinterpret_cast<const uint4*>(tp + gh0 * WID + ch * 8)
                                      : make_uint4(0u, 0u, 0u, 0u);
        bb.q = ((unsigned)gh1 < 256u) ? *reinterpret_cast<const uint4*>(tp + gh1 * WID + ch * 8)
                                      : make_uint4(0u, 0u, 0u, 0u);
        const int base = 5 * (1 + 8 * ch) + rp;
#pragma unroll
        for (int j = 0; j < 8; ++j)
            st32[base + 5 * j] = (uint)a.u[j] | ((uint)bb.u[j] << 16);
    }

    float wk0[9], wk1[9], wk2[25];
#pragma unroll
    for (int i = 0; i < 9; ++i)  wk0[i] = w0[c * 9 + i];
#pragma unroll
    for (int i = 0; i < 9; ++i)  wk1[i] = w1[c * 9 + i];
#pragma unroll
    for (int i = 0; i < 25; ++i) wk2[i] = w2[c * 25 + i];
    const float bb0 = b0[c], bb1 = b1[c], bb2 = b2[c];
    const float s0 = sw[b * 3 + 0], s1 = sw[b * 3 + 1], s2 = sw[b * 3 + 2];
    const float pr = 1.f + prompt[b * 96 + c];

    __syncthreads();

    const int w = tid;
    float acc0[8], acc1[8], acc2[8];
#pragma unroll
    for (int r = 0; r < 8; ++r) { acc0[r] = bb0; acc1[r] = bb1; acc2[r] = bb2; }

    const unsigned short* bx = &sxT[w * XPITCH];
    const unsigned short* bt = &stT[w * TPITCH];

#pragma unroll
    for (int kw = 0; kw < 5; ++kw) {
        float cv[20];
#pragma unroll
        for (int j = 0; j < 10; ++j) {
            unsigned u = *reinterpret_cast<const unsigned*>(&bx[kw * 3 * XPITCH + 2 * j]);
            cv[2 * j]     = lo2f(u);
            cv[2 * j + 1] = hi2f(u);
        }
#pragma unroll
        for (int kh = 0; kh < 5; ++kh) {
            const float wv = wk2[kh * 5 + kw];
#pragma unroll
            for (int r = 0; r < 8; ++r) acc2[r] += wv * cv[r + 3 * kh];
        }
        if (kw == 2) {
#pragma unroll
            for (int kh = 0; kh < 3; ++kh) {
                const float wv = wk1[kh * 3 + 1];
#pragma unroll
                for (int r = 0; r < 8; ++r) acc1[r] += wv * cv[r + 2 * kh + 4];
            }
        }
    }
#pragma unroll
    for (int kwh = 0; kwh < 2; ++kwh) {
        const int kw = kwh * 2;
        float cv[12];
#pragma unroll
        for (int j = 0; j < 6; ++j) {
            unsigned u = *reinterpret_cast<const unsigned*>(&bx[(4 + 2 * kw) * XPITCH + 4 + 2 * j]);
            cv[2 * j]     = lo2f(u);
            cv[2 * j + 1] = hi2f(u);
        }
#pragma unroll
        for (int kh = 0; kh < 3; ++kh) {
            const float wv = wk1[kh * 3 + kw];
#pragma unroll
            for (int r = 0; r < 8; ++r) acc1[r] += wv * cv[r + 2 * kh];
        }
    }
#pragma unroll
    for (int kw = 0; kw < 3; ++kw) {
        float cv[10];
#pragma unroll
        for (int j = 0; j < 5; ++j) {
            unsigned u = *reinterpret_cast<const unsigned*>(&bt[kw * TPITCH + 2 * j]);
            cv[2 * j]     = lo2f(u);
            cv[2 * j + 1] = hi2f(u);
        }
#pragma unroll
        for (int kh = 0; kh < 3; ++kh) {
            const float wv = wk0[kh * 3 + kw];
#pragma unroll
            for (int r = 0; r < 8; ++r) acc0[r] += wv * cv[r + kh];
        }
    }

    bf16* op = xa + pbase + (size_t)h0 * WID + w;
#pragma unroll
    for (int r = 0; r < 8; ++r) {
        float v = (s0 * acc0[r] + s1 * acc1[r] + s2 * acc2[r]) * pr;
        op[r * WID] = __float2bfloat16(v);
    }
}

// ---------------- launch ----------------
extern "C" void kernel_launch(void* const* d_in, const int* in_sizes, int n_in,
                              void* d_out, int out_size, void* d_ws, size_t ws_size,
                              hipStream_t stream)
{
    const float* x       = (const float*)d_in[0];
    const float* prompt  = (const float*)d_in[1];
    const float* sw      = (const float*)d_in[2];
    const float* ln_w    = (const float*)d_in[3];
    const float* ln_b    = (const float*)d_in[4];
    const float* e0_pw_w = (const float*)d_in[5];
    const float* e0_pw_b = (const float*)d_in[6];
    const float* e0_dw_w = (const float*)d_in[7];
    const float* e0_dw_b = (const float*)d_in[8];
    const float* e1_dw_w = (const float*)d_in[9];
    const float* e1_dw_b = (const float*)d_in[10];
    const float* e2_dw_w = (const float*)d_in[11];
    const float* e2_dw_b = (const float*)d_in[12];
    const float* proj_w  = (const float*)d_in[13];
    const float* proj_b  = (const float*)d_in[14];
    const float* ffn1_w  = (const float*)d_in[15];
    const float* ffn1_b  = (const float*)d_in[16];
    const float* ffn2_w  = (const float*)d_in[17];
    const float* ffn2_b  = (const float*)d_in[18];

    float* out = (float*)d_out;
    bf16*  ws  = (bf16*)d_ws;
    bf16*  A   = ws;                 // xn  bf16 (48 MB)
    bf16*  Bt  = ws + S_ELEMS;       // t0  bf16 (48 MB)
    bf16*  Cx  = ws + 2 * S_ELEMS;   // xa  bf16 (48 MB)

    // 1) xn = LayerNorm_c(x)
    ln_kernel<<<512, 256, 0, stream>>>(x, ln_w, ln_b, A);
    // 2) t0 = conv1x1(xn, e0_pw)
    conv1x1_mfma<bf16, bf16, 96, 96, false, false>
        <<<2048, 256, 0, stream>>>(A, e0_pw_w, e0_pw_b, nullptr, Bt);
    // 3) xa = (s0*dw3(t0) + s1*dw3d2(xn) + s2*dw5d3(xn)) * (1+prompt)
    experts_kernel<<<12288, 256, 0, stream>>>(A, Bt, e0_dw_w, e0_dw_b, e1_dw_w, e1_dw_b,
                                              e2_dw_w, e2_dw_b, sw, prompt, Cx);
    // 4) out = x1 + ffn2(gelu(ffn1(x1))), x1 = x + proj(xa)   [fused k4+k5+k6]
    ffn_fused<<<2048, 256, 0, stream>>>(Cx, x, proj_w, proj_b,
                                        ffn1_w, ffn1_b, ffn2_w, ffn2_b, out);
}

// Round 8
// 491.877 us; speedup vs baseline: 1.0072x; 1.0072x over previous
//
#include <hip/hip_runtime.h>
#include <hip/hip_bf16.h>

typedef __hip_bfloat16 bf16;
typedef __attribute__((ext_vector_type(8))) __bf16 bf16x8;
typedef __attribute__((ext_vector_type(4))) float  f32x4;

#define HW   65536
#define WID  256
#define CC   96
#define NB   4
static const size_t S_ELEMS = (size_t)NB * CC * HW;  // 25,165,824 elements

__device__ __forceinline__ float lo2f(unsigned u) { unsigned x = u << 16;        return __builtin_bit_cast(float, x); }
__device__ __forceinline__ float hi2f(unsigned u) { unsigned x = u & 0xffff0000u; return __builtin_bit_cast(float, x); }
__device__ __forceinline__ unsigned short f2bu(float f) {
    return __builtin_bit_cast(unsigned short, __float2bfloat16(f));
}

// exact-GELU via Abramowitz-Stegun 7.1.26 erf (|err| < 1.5e-7)
__device__ __forceinline__ float gelu_erf(float v) {
    float z  = fabsf(v) * 0.70710678118654752f;
    float t  = __builtin_amdgcn_rcpf(1.f + 0.3275911f * z);
    float poly = t * (0.254829592f + t * (-0.284496736f + t * (1.421413741f
               + t * (-1.453152027f + t * 1.061405429f))));
    float erfz = 1.f - poly * __expf(-z * z);
    float erfv = copysignf(erfz, v);
    return 0.5f * v * (1.f + erfv);
}

// ---------------- Kernel 1: LayerNorm over channel dim of NCHW ----------------
__global__ __launch_bounds__(256) void ln_kernel(
    const float* __restrict__ x, const float* __restrict__ lw,
    const float* __restrict__ lb, bf16* __restrict__ y)
{
    int t  = blockIdx.x * 256 + threadIdx.x;   // [0, 131072)
    int b  = t >> 15;
    int hw = (t & 32767) * 2;
    size_t base = (size_t)b * CC * HW + hw;

    float s0 = 0.f, s1 = 0.f, q0 = 0.f, q1 = 0.f;
    for (int c = 0; c < CC; ++c) {
        float2 v = *reinterpret_cast<const float2*>(&x[base + (size_t)c * HW]);
        s0 += v.x; s1 += v.y; q0 += v.x * v.x; q1 += v.y * v.y;
    }
    float mu0 = s0 * (1.f / 96.f), mu1 = s1 * (1.f / 96.f);
    float rs0 = rsqrtf(q0 * (1.f / 96.f) - mu0 * mu0 + 1e-6f);
    float rs1 = rsqrtf(q1 * (1.f / 96.f) - mu1 * mu1 + 1e-6f);

    for (int c = 0; c < CC; ++c) {
        float2 v = *reinterpret_cast<const float2*>(&x[base + (size_t)c * HW]);
        float g = lw[c], be = lb[c];
        bf16 o[2];
        o[0] = __float2bfloat16((v.x - mu0) * rs0 * g + be);
        o[1] = __float2bfloat16((v.y - mu1) * rs1 * g + be);
        *reinterpret_cast<uint*>(&y[base + (size_t)c * HW]) = *reinterpret_cast<uint*>(o);
    }
}

// ---------------- conv1x1 via MFMA 16x16x32 bf16 (k2 only) -------------------
__device__ __forceinline__ int swzo(int row, int col, int width) {
    return (row * width + col) ^ ((((row & 7) ^ ((row >> 3) & 7)) << 3));
}

template <typename TI, typename TOT, int CIN, int COUT, bool GELU, bool HASRES>
__global__ __launch_bounds__(256) void conv1x1_mfma(
    const TI* __restrict__ in, const float* __restrict__ wgt,
    const float* __restrict__ bias, const float* __restrict__ resid,
    TOT* __restrict__ out)
{
    constexpr int KSPLIT = CIN / 96;
    constexpr int OSPLIT = COUT / 96;
    constexpr int MT     = 6;
    static_assert(CIN == KSPLIT * 96 && COUT == OSPLIT * 96, "96-multiples only");

    __shared__ unsigned short s_w[96 * 96];
    __shared__ unsigned short s_x[128 * 96];
    __shared__ float          s_b[COUT];

    const int tid  = threadIdx.x;
    const int lane = tid & 63;
    const int wave = tid >> 6;
    const int q    = lane >> 4;
    const int n    = lane & 15;

    const int pos0 = blockIdx.x * 128;
    const int b    = pos0 >> 16;
    const int hw0  = pos0 & 65535;

    for (int k = tid; k < COUT; k += 256) s_b[k] = bias[k];

    const TI* inb = in + (size_t)b * CIN * HW;
    const int pl0 = wave * 32 + n;
    const int pl1 = pl0 + 16;

#pragma unroll
    for (int os = 0; os < OSPLIT; ++os) {
        f32x4 acc[MT][2];
#pragma unroll
        for (int mt = 0; mt < MT; ++mt) {
            acc[mt][0] = {0.f, 0.f, 0.f, 0.f};
            acc[mt][1] = {0.f, 0.f, 0.f, 0.f};
        }

#pragma unroll
        for (int ks = 0; ks < KSPLIT; ++ks) {
            for (int k = tid; k < 96 * 24; k += 256) {
                int o = k / 24, c4 = (k - o * 24) * 4;
                float4 w4 = *reinterpret_cast<const float4*>(
                    &wgt[(size_t)(os * 96 + o) * CIN + ks * 96 + c4]);
                ushort4 pk = make_ushort4(f2bu(w4.x), f2bu(w4.y), f2bu(w4.z), f2bu(w4.w));
                *reinterpret_cast<ushort4*>(&s_w[swzo(o, c4, 96)]) = pk;
            }
            if (KSPLIT > 1 || os == 0) {
                for (int idx = tid; idx < 48 * 16; idx += 256) {
                    const int cp = idx >> 4;
                    const int pb = idx & 15;
                    const TI* gp = inb + (size_t)(ks * 96 + 2 * cp) * HW + hw0 + pb * 8;
                    unsigned short ua[8], ub[8];
                    if constexpr (__is_same(TI, float)) {
                        float4 a0 = *reinterpret_cast<const float4*>(gp);
                        float4 a1 = *reinterpret_cast<const float4*>(gp + 4);
                        float4 b0 = *reinterpret_cast<const float4*>(gp + HW);
                        float4 b1 = *reinterpret_cast<const float4*>(gp + HW + 4);
                        ua[0]=f2bu(a0.x); ua[1]=f2bu(a0.y); ua[2]=f2bu(a0.z); ua[3]=f2bu(a0.w);
                        ua[4]=f2bu(a1.x); ua[5]=f2bu(a1.y); ua[6]=f2bu(a1.z); ua[7]=f2bu(a1.w);
                        ub[0]=f2bu(b0.x); ub[1]=f2bu(b0.y); ub[2]=f2bu(b0.z); ub[3]=f2bu(b0.w);
                        ub[4]=f2bu(b1.x); ub[5]=f2bu(b1.y); ub[6]=f2bu(b1.z); ub[7]=f2bu(b1.w);
                    } else {
                        *reinterpret_cast<uint4*>(ua) = *reinterpret_cast<const uint4*>(gp);
                        *reinterpret_cast<uint4*>(ub) = *reinterpret_cast<const uint4*>(gp + HW);
                    }
#pragma unroll
                    for (int i = 0; i < 8; ++i) {
                        uint d = (uint)ua[i] | ((uint)ub[i] << 16);
                        *reinterpret_cast<uint*>(&s_x[swzo(pb * 8 + i, 2 * cp, 96)]) = d;
                    }
                }
            }
            __syncthreads();

#pragma unroll
            for (int kt = 0; kt < 3; ++kt) {
                const int col = kt * 32 + q * 8;
                union { unsigned short u[8]; bf16x8 v; } bf0, bf1;
                *reinterpret_cast<uint4*>(bf0.u) =
                    *reinterpret_cast<const uint4*>(&s_x[swzo(pl0, col, 96)]);
                *reinterpret_cast<uint4*>(bf1.u) =
                    *reinterpret_cast<const uint4*>(&s_x[swzo(pl1, col, 96)]);
#pragma unroll
                for (int mt = 0; mt < MT; ++mt) {
                    union { unsigned short u[8]; bf16x8 v; } fa;
                    *reinterpret_cast<uint4*>(fa.u) =
                        *reinterpret_cast<const uint4*>(&s_w[swzo(mt * 16 + n, col, 96)]);
                    acc[mt][0] = __builtin_amdgcn_mfma_f32_16x16x32_bf16(fa.v, bf0.v, acc[mt][0], 0, 0, 0);
                    acc[mt][1] = __builtin_amdgcn_mfma_f32_16x16x32_bf16(fa.v, bf1.v, acc[mt][1], 0, 0, 0);
                }
            }
            if (os + 1 < OSPLIT || ks + 1 < KSPLIT)
                __syncthreads();
        }

        const int p0 = hw0 + pl0;
        const int p1 = hw0 + pl1;
        const size_t obase = (size_t)b * COUT * HW;
#pragma unroll
        for (int mt = 0; mt < MT; ++mt) {
#pragma unroll
            for (int nt = 0; nt < 2; ++nt) {
                const int p = (nt == 0) ? p0 : p1;
#pragma unroll
                for (int r = 0; r < 4; ++r) {
                    const int o = os * 96 + mt * 16 + q * 4 + r;
                    float v = acc[mt][nt][r] + s_b[o];
                    if constexpr (GELU) v = gelu_erf(v);
                    const size_t idx = obase + (size_t)o * HW + p;
                    if constexpr (HASRES) v += resid[idx];
                    if constexpr (__is_same(TOT, float)) out[idx] = v;
                    else                                 out[idx] = __float2bfloat16(v);
                }
            }
        }
    }
}

// ---------------- Fused FFN v2: out = x1 + ffn2(gelu(ffn1(x1))), x1 = x+proj(xa)
// 512 threads (8 waves x 16 positions). ALL LDS tiles in the proven swzo-96
// layout (round-7 bug: HP=104 = 52 dwords EVEN pitch -> 8-way read conflicts).
// Phase order proj -> g1h0 -> g2k0 -> g1h1 -> g2k1; each W slice is global-
// loaded into regs during the PRECEDING GEMM phase (T14 split) and ds_written
// in a cheap write-phase, so no global latency sits on a barrier.
// LDS 69.1 KB -> 2 blocks/CU = 16 waves/CU; launch_bounds caps VGPR at 128.
__global__ __launch_bounds__(512, 4) void ffn_fused(
    const bf16* __restrict__ xa, const float* __restrict__ x,
    const float* __restrict__ pw, const float* __restrict__ pb,
    const float* __restrict__ w1, const float* __restrict__ b1,
    const float* __restrict__ w2, const float* __restrict__ b2,
    float* __restrict__ out)
{
    __shared__ unsigned short s_w[96 * 96];     // 18,432 B  current W slice
    __shared__ unsigned short s_x1[128 * 96];   // 24,576 B  x1 bf16 (swz96)
    __shared__ unsigned short s_hx[128 * 96];   // 24,576 B  xa -> h0 -> h1
    __shared__ float          s_bias[384];      // pb[96] | b1[192] | b2[96]

    const int tid  = threadIdx.x;
    const int lane = tid & 63;
    const int w8   = tid >> 6;                  // wave 0..7
    const int q    = lane >> 4;
    const int n    = lane & 15;

    const int pos0 = blockIdx.x * 128;
    const int b    = pos0 >> 16;
    const int hw0  = pos0 & 65535;
    const int pl   = w8 * 16 + n;               // tile-local position
    const int p    = hw0 + pl;                  // global position

    // ---- weight slice preload regs (items idx = tid + i*512 of 96x24 float4)
    float4 wr[5];
    auto WLOAD = [&](const float* W, int row0, int col0, int rs) {
#pragma unroll
        for (int i = 0; i < 5; ++i) {
            const int idx = tid + i * 512;
            if (i < 4 || tid < 256) {
                const int o = idx / 24, c4 = (idx - o * 24) * 4;
                wr[i] = *reinterpret_cast<const float4*>(
                    &W[(size_t)(row0 + o) * rs + col0 + c4]);
            }
        }
    };
    auto WWRITE = [&]() {
#pragma unroll
        for (int i = 0; i < 5; ++i) {
            const int idx = tid + i * 512;
            if (i < 4 || tid < 256) {
                const int o = idx / 24, c4 = (idx - o * 24) * 4;
                ushort4 pk = make_ushort4(f2bu(wr[i].x), f2bu(wr[i].y),
                                          f2bu(wr[i].z), f2bu(wr[i].w));
                *reinterpret_cast<ushort4*>(&s_w[swzo(o, c4, 96)]) = pk;
            }
        }
    };
    auto GEMM = [&](const unsigned short* B, f32x4 (&acc)[6]) {
#pragma unroll
        for (int kt = 0; kt < 3; ++kt) {
            const int col = kt * 32 + q * 8;
            union { unsigned short u[8]; bf16x8 v; } bf;
            *reinterpret_cast<uint4*>(bf.u) =
                *reinterpret_cast<const uint4*>(&B[swzo(pl, col, 96)]);
#pragma unroll
            for (int mt = 0; mt < 6; ++mt) {
                union { unsigned short u[8]; bf16x8 v; } fa;
                *reinterpret_cast<uint4*>(fa.u) =
                    *reinterpret_cast<const uint4*>(&s_w[swzo(mt * 16 + n, col, 96)]);
                acc[mt] = __builtin_amdgcn_mfma_f32_16x16x32_bf16(fa.v, bf.v, acc[mt], 0, 0, 0);
            }
        }
    };
    auto ST4 = [&](unsigned short* dst, int col4, float v0, float v1, float v2, float v3) {
        union { unsigned short u[4]; uint2 d; } t;
        t.u[0] = f2bu(v0); t.u[1] = f2bu(v1); t.u[2] = f2bu(v2); t.u[3] = f2bu(v3);
        *reinterpret_cast<uint2*>(&dst[swzo(pl, col4, 96)]) = t.d;  // col4%8 in {0,4}
    };

    // ---------- S0: xa -> s_hx (swz96), proj W -> s_w direct, biases
    {
        const bf16* inb = xa + (size_t)b * 96 * HW;
        for (int idx = tid; idx < 48 * 16; idx += 512) {
            const int cp = idx >> 4, pbk = idx & 15;
            const bf16* gp = inb + (size_t)(2 * cp) * HW + hw0 + pbk * 8;
            unsigned short ua[8], ub[8];
            *reinterpret_cast<uint4*>(ua) = *reinterpret_cast<const uint4*>(gp);
            *reinterpret_cast<uint4*>(ub) = *reinterpret_cast<const uint4*>(gp + HW);
#pragma unroll
            for (int i = 0; i < 8; ++i) {
                uint d = (uint)ua[i] | ((uint)ub[i] << 16);
                *reinterpret_cast<uint*>(&s_hx[swzo(pbk * 8 + i, 2 * cp, 96)]) = d;
            }
        }
        for (int k = tid; k < 96 * 24; k += 512) {
            const int o = k / 24, c4 = (k - o * 24) * 4;
            float4 w4 = *reinterpret_cast<const float4*>(&pw[(size_t)o * 96 + c4]);
            ushort4 pk = make_ushort4(f2bu(w4.x), f2bu(w4.y), f2bu(w4.z), f2bu(w4.w));
            *reinterpret_cast<ushort4*>(&s_w[swzo(o, c4, 96)]) = pk;
        }
        if (tid < 96)  s_bias[tid]       = pb[tid];
        if (tid < 192) s_bias[96 + tid]  = b1[tid];
        if (tid < 96)  s_bias[288 + tid] = b2[tid];
    }
    __syncthreads();

    // ---------- P1: proj GEMM (+ preload w1h0, + x resid loads)
    WLOAD(w1, 0, 0, 96);
    float xr[6][4];
    {
        const size_t xbase = (size_t)b * 96 * HW;
#pragma unroll
        for (int mt = 0; mt < 6; ++mt)
#pragma unroll
            for (int r = 0; r < 4; ++r)
                xr[mt][r] = x[xbase + (size_t)(mt * 16 + q * 4 + r) * HW + p];
    }
    float x1f[6][4];
    {
        f32x4 accp[6];
#pragma unroll
        for (int mt = 0; mt < 6; ++mt) accp[mt] = {0.f, 0.f, 0.f, 0.f};
        GEMM(s_hx, accp);
#pragma unroll
        for (int mt = 0; mt < 6; ++mt) {
#pragma unroll
            for (int r = 0; r < 4; ++r)
                x1f[mt][r] = accp[mt][r] + s_bias[mt * 16 + q * 4 + r] + xr[mt][r];
            ST4(s_x1, mt * 16 + q * 4, x1f[mt][0], x1f[mt][1], x1f[mt][2], x1f[mt][3]);
        }
    }
    __syncthreads();

    // ---------- P2: write w1h0
    WWRITE();
    __syncthreads();

    // ---------- P3: GEMM1 h0 (+ preload w2k0); h0 -> s_hx (xa dead)
    WLOAD(w2, 0, 0, 192);
    {
        f32x4 a1[6];
#pragma unroll
        for (int mt = 0; mt < 6; ++mt) a1[mt] = {0.f, 0.f, 0.f, 0.f};
        GEMM(s_x1, a1);
#pragma unroll
        for (int mt = 0; mt < 6; ++mt) {
            float v0 = gelu_erf(a1[mt][0] + s_bias[96 + mt * 16 + q * 4 + 0]);
            float v1 = gelu_erf(a1[mt][1] + s_bias[96 + mt * 16 + q * 4 + 1]);
            float v2 = gelu_erf(a1[mt][2] + s_bias[96 + mt * 16 + q * 4 + 2]);
            float v3 = gelu_erf(a1[mt][3] + s_bias[96 + mt * 16 + q * 4 + 3]);
            ST4(s_hx, mt * 16 + q * 4, v0, v1, v2, v3);
        }
    }
    __syncthreads();

    // ---------- P4: write w2k0
    WWRITE();
    __syncthreads();

    // ---------- P5: GEMM2 k0 (+ preload w1h1)
    f32x4 acc2[6];
#pragma unroll
    for (int mt = 0; mt < 6; ++mt) acc2[mt] = {0.f, 0.f, 0.f, 0.f};
    WLOAD(w1, 96, 0, 96);
    GEMM(s_hx, acc2);
    __syncthreads();

    // ---------- P6: write w1h1
    WWRITE();
    __syncthreads();

    // ---------- P7: GEMM1 h1 (+ preload w2k1); h1 -> s_hx (h0 dead)
    WLOAD(w2, 0, 96, 192);
    {
        f32x4 a1[6];
#pragma unroll
        for (int mt = 0; mt < 6; ++mt) a1[mt] = {0.f, 0.f, 0.f, 0.f};
        GEMM(s_x1, a1);
#pragma unroll
        for (int mt = 0; mt < 6; ++mt) {
            float v0 = gelu_erf(a1[mt][0] + s_bias[192 + mt * 16 + q * 4 + 0]);
            float v1 = gelu_erf(a1[mt][1] + s_bias[192 + mt * 16 + q * 4 + 1]);
            float v2 = gelu_erf(a1[mt][2] + s_bias[192 + mt * 16 + q * 4 + 2]);
            float v3 = gelu_erf(a1[mt][3] + s_bias[192 + mt * 16 + q * 4 + 3]);
            ST4(s_hx, mt * 16 + q * 4, v0, v1, v2, v3);
        }
    }
    __syncthreads();

    // ---------- P8: write w2k1
    WWRITE();
    __syncthreads();

    // ---------- P9: GEMM2 k1 + epilogue (out written exactly once)
    GEMM(s_hx, acc2);
    {
        const size_t obase = (size_t)b * 96 * HW;
#pragma unroll
        for (int mt = 0; mt < 6; ++mt)
#pragma unroll
            for (int r = 0; r < 4; ++r) {
                const int o = mt * 16 + q * 4 + r;
                out[obase + (size_t)o * HW + p] = x1f[mt][r] + acc2[mt][r] + s_bias[288 + o];
            }
    }
}

// ---------------- Kernel 3: experts, TRANSPOSED LDS stencil ----------------
#define XR     20
#define XPITCH 22      // 11 dwords (odd)
#define TPITCH 10      // 5 dwords (odd)
#define XCOLS  268
#define TCOLS  258

__global__ __launch_bounds__(256) void experts_kernel(
    const bf16* __restrict__ xn, const bf16* __restrict__ t0,
    const float* __restrict__ w0, const float* __restrict__ b0,
    const float* __restrict__ w1, const float* __restrict__ b1,
    const float* __restrict__ w2, const float* __restrict__ b2,
    const float* __restrict__ sw, const float* __restrict__ prompt,
    bf16* __restrict__ xa)
{
    __shared__ alignas(16) unsigned short sxT[XCOLS * XPITCH];
    __shared__ alignas(16) unsigned short stT[TCOLS * TPITCH];

    const int tid  = threadIdx.x;
    const int lane = tid & 63;
    const int wave = tid >> 6;
    const int bid = blockIdx.x;
    const int h0  = (bid & 31) * 8;
    const int bc  = bid >> 5;
    const int b   = bc / 96;
    const int c   = bc - b * 96;
    const size_t pbase = (size_t)bc * HW;

    const bf16* xp = xn + pbase;
    const bf16* tp = t0 + pbase;
    uint* sx32 = reinterpret_cast<uint*>(sxT);
    uint* st32 = reinterpret_cast<uint*>(stT);

    if (tid < 132) {
        int cc = tid / 11, d = tid - cc * 11;
        int col = (cc < 6) ? cc : 256 + cc;
        sx32[col * 11 + d] = 0u;
    } else if (tid < 142) {
        int i = tid - 132;
        int col = (i < 5) ? 0 : 257;
        int d   = (i < 5) ? i : i - 5;
        st32[col * 5 + d] = 0u;
    }

    {
        const int rp = (lane >> 2) & 7;
        const int ch = 8 * wave + (lane & 3) + ((lane >> 5) << 2);
        const int gh0 = h0 - 6 + 2 * rp, gh1 = gh0 + 1;
        union { uint4 q; unsigned short u[8]; } a, bb;
        a.q  = ((unsigned)gh0 < 256u) ? *reinterpret_cast<const uint4*>(xp + gh0 * WID + ch * 8)
                                      : make_uint4(0u, 0u, 0u, 0u);
        bb.q = ((unsigned)gh1 < 256u) ? *reinterpret_cast<const uint4*>(xp + gh1 * WID + ch * 8)
                                      : make_uint4(0u, 0u, 0u, 0u);
        const int base = 11 * (6 + 8 * ch) + rp;
#pragma unroll
        for (int j = 0; j < 8; ++j)
            sx32[base + 11 * j] = (uint)a.u[j] | ((uint)bb.u[j] << 16);
    }
    if (wave == 2) {
        const int rp = 8 + ((lane >> 2) & 1);
        const int ch = (lane & 3) + (((lane >> 3) & 7) << 2);
        const int gh0 = h0 - 6 + 2 * rp, gh1 = gh0 + 1;
        union { uint4 q; unsigned short u[8]; } a, bb;
        a.q  = ((unsigned)gh0 < 256u) ? *reinterpret_cast<const uint4*>(xp + gh0 * WID + ch * 8)
                                      : make_uint4(0u, 0u, 0u, 0u);
        bb.q = ((unsigned)gh1 < 256u) ? *reinterpret_cast<const uint4*>(xp + gh1 * WID + ch * 8)
                                      : make_uint4(0u, 0u, 0u, 0u);
        const int base = 11 * (6 + 8 * ch) + rp;
#pragma unroll
        for (int j = 0; j < 8; ++j)
            sx32[base + 11 * j] = (uint)a.u[j] | ((uint)bb.u[j] << 16);
    }
    if (wave < 2) {
        const int rp = (lane >> 3) & 3;
        const int ch = 16 * wave + (lane & 7) + ((lane >> 5) << 3);
        const int gh0 = h0 - 1 + 2 * rp, gh1 = gh0 + 1;
        union { uint4 q; unsigned short u[8]; } a, bb;
        a.q  = ((unsigned)gh0 < 256u) ? *reinterpret_cast<const uint4*>(tp + gh0 * WID + ch * 8)
                                      : make_uint4(0u, 0u, 0u, 0u);
        bb.q = ((unsigned)gh1 < 256u) ? *reinterpret_cast<const uint4*>(tp + gh1 * WID + ch * 8)
                                      : make_uint4(0u, 0u, 0u, 0u);
        const int base = 5 * (1 + 8 * ch) + rp;
#pragma unroll
        for (int j = 0; j < 8; ++j)
            st32[base + 5 * j] = (uint)a.u[j] | ((uint)bb.u[j] << 16);
    }
    if (wave == 3 && lane < 32) {
        const int rp = 4;
        const int ch = lane;
        const int gh0 = h0 - 1 + 2 * rp, gh1 = gh0 + 1;
        union { uint4 q; unsigned short u[8]; } a, bb;
        a.q  = ((unsigned)gh0 < 256u) ? *reinterpret_cast<const uint4*>(tp + gh0 * WID + ch * 8)
                                      : make_uint4(0u, 0u, 0u, 0u);
        bb.q = ((unsigned)gh1 < 256u) ? *reinterpret_cast<const uint4*>(tp + gh1 * WID + ch * 8)
                                      : make_uint4(0u, 0u, 0u, 0u);
        const int base = 5 * (1 + 8 * ch) + rp;
#pragma unroll
        for (int j = 0; j < 8; ++j)
            st32[base + 5 * j] = (uint)a.u[j] | ((uint)bb.u[j] << 16);
    }

    float wk0[9], wk1[9], wk2[25];
#pragma unroll
    for (int i = 0; i < 9; ++i)  wk0[i] = w0[c * 9 + i];
#pragma unroll
    for (int i = 0; i < 9; ++i)  wk1[i] = w1[c * 9 + i];
#pragma unroll
    for (int i = 0; i < 25; ++i) wk2[i] = w2[c * 25 + i];
    const float bb0 = b0[c], bb1 = b1[c], bb2 = b2[c];
    const float s0 = sw[b * 3 + 0], s1 = sw[b * 3 + 1], s2 = sw[b * 3 + 2];
    const float pr = 1.f + prompt[b * 96 + c];

    __syncthreads();

    const int w = tid;
    float acc0[8], acc1[8], acc2[8];
#pragma unroll
    for (int r = 0; r < 8; ++r) { acc0[r] = bb0; acc1[r] = bb1; acc2[r] = bb2; }

    const unsigned short* bx = &sxT[w * XPITCH];
    const unsigned short* bt = &stT[w * TPITCH];

#pragma unroll
    for (int kw = 0; kw < 5; ++kw) {
        float cv[20];
#pragma unroll
        for (int j = 0; j < 10; ++j) {
            unsigned u = *reinterpret_cast<const unsigned*>(&bx[kw * 3 * XPITCH + 2 * j]);
            cv[2 * j]     = lo2f(u);
            cv[2 * j + 1] = hi2f(u);
        }
#pragma unroll
        for (int kh = 0; kh < 5; ++kh) {
            const float wv = wk2[kh * 5 + kw];
#pragma unroll
            for (int r = 0; r < 8; ++r) acc2[r] += wv * cv[r + 3 * kh];
        }
        if (kw == 2) {
#pragma unroll
            for (int kh = 0; kh < 3; ++kh) {
                const float wv = wk1[kh * 3 + 1];
#pragma unroll
                for (int r = 0; r < 8; ++r) acc1[r] += wv * cv[r + 2 * kh + 4];
            }
        }
    }
#pragma unroll
    for (int kwh = 0; kwh < 2; ++kwh) {
        const int kw = kwh * 2;
        float cv[12];
#pragma unroll
        for (int j = 0; j < 6; ++j) {
            unsigned u = *reinterpret_cast<const unsigned*>(&bx[(4 + 2 * kw) * XPITCH + 4 + 2 * j]);
            cv[2 * j]     = lo2f(u);
            cv[2 * j + 1] = hi2f(u);
        }
#pragma unroll
        for (int kh = 0; kh < 3; ++kh) {
            const float wv = wk1[kh * 3 + kw];
#pragma unroll
            for (int r = 0; r < 8; ++r) acc1[r] += wv * cv[r + 2 * kh];
        }
    }
#pragma unroll
    for (int kw = 0; kw < 3; ++kw) {
        float cv[10];
#pragma unroll
        for (int j = 0; j < 5; ++j) {
            unsigned u = *reinterpret_cast<const unsigned*>(&bt[kw * TPITCH + 2 * j]);
            cv[2 * j]     = lo2f(u);
            cv[2 * j + 1] = hi2f(u);
        }
#pragma unroll
        for (int kh = 0; kh < 3; ++kh) {
            const float wv = wk0[kh * 3 + kw];
#pragma unroll
            for (int r = 0; r < 8; ++r) acc0[r] += wv * cv[r + kh];
        }
    }

    bf16* op = xa + pbase + (size_t)h0 * WID + w;
#pragma unroll
    for (int r = 0; r < 8; ++r) {
        float v = (s0 * acc0[r] + s1 * acc1[r] + s2 * acc2[r]) * pr;
        op[r * WID] = __float2bfloat16(v);
    }
}

// ---------------- launch ----------------
extern "C" void kernel_launch(void* const* d_in, const int* in_sizes, int n_in,
                              void* d_out, int out_size, void* d_ws, size_t ws_size,
                              hipStream_t stream)
{
    const float* x       = (const float*)d_in[0];
    const float* prompt  = (const float*)d_in[1];
    const float* sw      = (const float*)d_in[2];
    const float* ln_w    = (const float*)d_in[3];
    const float* ln_b    = (const float*)d_in[4];
    const float* e0_pw_w = (const float*)d_in[5];
    const float* e0_pw_b = (const float*)d_in[6];
    const float* e0_dw_w = (const float*)d_in[7];
    const float* e0_dw_b = (const float*)d_in[8];
    const float* e1_dw_w = (const float*)d_in[9];
    const float* e1_dw_b = (const float*)d_in[10];
    const float* e2_dw_w = (const float*)d_in[11];
    const float* e2_dw_b = (const float*)d_in[12];
    const float* proj_w  = (const float*)d_in[13];
    const float* proj_b  = (const float*)d_in[14];
    const float* ffn1_w  = (const float*)d_in[15];
    const float* ffn1_b  = (const float*)d_in[16];
    const float* ffn2_w  = (const float*)d_in[17];
    const float* ffn2_b  = (const float*)d_in[18];

    float* out = (float*)d_out;
    bf16*  ws  = (bf16*)d_ws;
    bf16*  A   = ws;                 // xn  bf16 (48 MB)
    bf16*  Bt  = ws + S_ELEMS;       // t0  bf16 (48 MB)
    bf16*  Cx  = ws + 2 * S_ELEMS;   // xa  bf16 (48 MB)

    // 1) xn = LayerNorm_c(x)
    ln_kernel<<<512, 256, 0, stream>>>(x, ln_w, ln_b, A);
    // 2) t0 = conv1x1(xn, e0_pw)
    conv1x1_mfma<bf16, bf16, 96, 96, false, false>
        <<<2048, 256, 0, stream>>>(A, e0_pw_w, e0_pw_b, nullptr, Bt);
    // 3) xa = (s0*dw3(t0) + s1*dw3d2(xn) + s2*dw5d3(xn)) * (1+prompt)
    experts_kernel<<<12288, 256, 0, stream>>>(A, Bt, e0_dw_w, e0_dw_b, e1_dw_w, e1_dw_b,
                                              e2_dw_w, e2_dw_b, sw, prompt, Cx);
    // 4) out = x1 + ffn2(gelu(ffn1(x1))), x1 = x + proj(xa)   [fused k4+k5+k6]
    ffn_fused<<<2048, 512, 0, stream>>>(Cx, x, proj_w, proj_b,
                                        ffn1_w, ffn1_b, ffn2_w, ffn2_b, out);
}

// Round 9
// 466.070 us; speedup vs baseline: 1.0630x; 1.0554x over previous
//
#include <hip/hip_runtime.h>
#include <hip/hip_bf16.h>

typedef __hip_bfloat16 bf16;
typedef __attribute__((ext_vector_type(8))) __bf16 bf16x8;
typedef __attribute__((ext_vector_type(4))) float  f32x4;

#define HW   65536
#define WID  256
#define CC   96
#define NB   4
static const size_t S_ELEMS = (size_t)NB * CC * HW;  // 25,165,824 elements

__device__ __forceinline__ float lo2f(unsigned u) { unsigned x = u << 16;        return __builtin_bit_cast(float, x); }
__device__ __forceinline__ float hi2f(unsigned u) { unsigned x = u & 0xffff0000u; return __builtin_bit_cast(float, x); }
__device__ __forceinline__ unsigned short f2bu(float f) {
    return __builtin_bit_cast(unsigned short, __float2bfloat16(f));
}

// exact-GELU via Abramowitz-Stegun 7.1.26 erf (|err| < 1.5e-7)
__device__ __forceinline__ float gelu_erf(float v) {
    float z  = fabsf(v) * 0.70710678118654752f;
    float t  = __builtin_amdgcn_rcpf(1.f + 0.3275911f * z);
    float poly = t * (0.254829592f + t * (-0.284496736f + t * (1.421413741f
               + t * (-1.453152027f + t * 1.061405429f))));
    float erfz = 1.f - poly * __expf(-z * z);
    float erfv = copysignf(erfz, v);
    return 0.5f * v * (1.f + erfv);
}

// ---------------- Kernel 1: LayerNorm over channel dim of NCHW ----------------
__global__ __launch_bounds__(256) void ln_kernel(
    const float* __restrict__ x, const float* __restrict__ lw,
    const float* __restrict__ lb, bf16* __restrict__ y)
{
    int t  = blockIdx.x * 256 + threadIdx.x;   // [0, 131072)
    int b  = t >> 15;
    int hw = (t & 32767) * 2;
    size_t base = (size_t)b * CC * HW + hw;

    float s0 = 0.f, s1 = 0.f, q0 = 0.f, q1 = 0.f;
    for (int c = 0; c < CC; ++c) {
        float2 v = *reinterpret_cast<const float2*>(&x[base + (size_t)c * HW]);
        s0 += v.x; s1 += v.y; q0 += v.x * v.x; q1 += v.y * v.y;
    }
    float mu0 = s0 * (1.f / 96.f), mu1 = s1 * (1.f / 96.f);
    float rs0 = rsqrtf(q0 * (1.f / 96.f) - mu0 * mu0 + 1e-6f);
    float rs1 = rsqrtf(q1 * (1.f / 96.f) - mu1 * mu1 + 1e-6f);

    for (int c = 0; c < CC; ++c) {
        float2 v = *reinterpret_cast<const float2*>(&x[base + (size_t)c * HW]);
        float g = lw[c], be = lb[c];
        bf16 o[2];
        o[0] = __float2bfloat16((v.x - mu0) * rs0 * g + be);
        o[1] = __float2bfloat16((v.y - mu1) * rs1 * g + be);
        *reinterpret_cast<uint*>(&y[base + (size_t)c * HW]) = *reinterpret_cast<uint*>(o);
    }
}

// ---------------- conv1x1 via MFMA 16x16x32 bf16 (k2 only) -------------------
__device__ __forceinline__ int swzo(int row, int col, int width) {
    return (row * width + col) ^ ((((row & 7) ^ ((row >> 3) & 7)) << 3));
}

template <typename TI, typename TOT, int CIN, int COUT, bool GELU, bool HASRES>
__global__ __launch_bounds__(256) void conv1x1_mfma(
    const TI* __restrict__ in, const float* __restrict__ wgt,
    const float* __restrict__ bias, const float* __restrict__ resid,
    TOT* __restrict__ out)
{
    constexpr int KSPLIT = CIN / 96;
    constexpr int OSPLIT = COUT / 96;
    constexpr int MT     = 6;
    static_assert(CIN == KSPLIT * 96 && COUT == OSPLIT * 96, "96-multiples only");

    __shared__ unsigned short s_w[96 * 96];
    __shared__ unsigned short s_x[128 * 96];
    __shared__ float          s_b[COUT];

    const int tid  = threadIdx.x;
    const int lane = tid & 63;
    const int wave = tid >> 6;
    const int q    = lane >> 4;
    const int n    = lane & 15;

    const int pos0 = blockIdx.x * 128;
    const int b    = pos0 >> 16;
    const int hw0  = pos0 & 65535;

    for (int k = tid; k < COUT; k += 256) s_b[k] = bias[k];

    const TI* inb = in + (size_t)b * CIN * HW;
    const int pl0 = wave * 32 + n;
    const int pl1 = pl0 + 16;

#pragma unroll
    for (int os = 0; os < OSPLIT; ++os) {
        f32x4 acc[MT][2];
#pragma unroll
        for (int mt = 0; mt < MT; ++mt) {
            acc[mt][0] = {0.f, 0.f, 0.f, 0.f};
            acc[mt][1] = {0.f, 0.f, 0.f, 0.f};
        }

#pragma unroll
        for (int ks = 0; ks < KSPLIT; ++ks) {
            for (int k = tid; k < 96 * 24; k += 256) {
                int o = k / 24, c4 = (k - o * 24) * 4;
                float4 w4 = *reinterpret_cast<const float4*>(
                    &wgt[(size_t)(os * 96 + o) * CIN + ks * 96 + c4]);
                ushort4 pk = make_ushort4(f2bu(w4.x), f2bu(w4.y), f2bu(w4.z), f2bu(w4.w));
                *reinterpret_cast<ushort4*>(&s_w[swzo(o, c4, 96)]) = pk;
            }
            if (KSPLIT > 1 || os == 0) {
                for (int idx = tid; idx < 48 * 16; idx += 256) {
                    const int cp = idx >> 4;
                    const int pb = idx & 15;
                    const TI* gp = inb + (size_t)(ks * 96 + 2 * cp) * HW + hw0 + pb * 8;
                    unsigned short ua[8], ub[8];
                    if constexpr (__is_same(TI, float)) {
                        float4 a0 = *reinterpret_cast<const float4*>(gp);
                        float4 a1 = *reinterpret_cast<const float4*>(gp + 4);
                        float4 b0 = *reinterpret_cast<const float4*>(gp + HW);
                        float4 b1 = *reinterpret_cast<const float4*>(gp + HW + 4);
                        ua[0]=f2bu(a0.x); ua[1]=f2bu(a0.y); ua[2]=f2bu(a0.z); ua[3]=f2bu(a0.w);
                        ua[4]=f2bu(a1.x); ua[5]=f2bu(a1.y); ua[6]=f2bu(a1.z); ua[7]=f2bu(a1.w);
                        ub[0]=f2bu(b0.x); ub[1]=f2bu(b0.y); ub[2]=f2bu(b0.z); ub[3]=f2bu(b0.w);
                        ub[4]=f2bu(b1.x); ub[5]=f2bu(b1.y); ub[6]=f2bu(b1.z); ub[7]=f2bu(b1.w);
                    } else {
                        *reinterpret_cast<uint4*>(ua) = *reinterpret_cast<const uint4*>(gp);
                        *reinterpret_cast<uint4*>(ub) = *reinterpret_cast<const uint4*>(gp + HW);
                    }
#pragma unroll
                    for (int i = 0; i < 8; ++i) {
                        uint d = (uint)ua[i] | ((uint)ub[i] << 16);
                        *reinterpret_cast<uint*>(&s_x[swzo(pb * 8 + i, 2 * cp, 96)]) = d;
                    }
                }
            }
            __syncthreads();

#pragma unroll
            for (int kt = 0; kt < 3; ++kt) {
                const int col = kt * 32 + q * 8;
                union { unsigned short u[8]; bf16x8 v; } bf0, bf1;
                *reinterpret_cast<uint4*>(bf0.u) =
                    *reinterpret_cast<const uint4*>(&s_x[swzo(pl0, col, 96)]);
                *reinterpret_cast<uint4*>(bf1.u) =
                    *reinterpret_cast<const uint4*>(&s_x[swzo(pl1, col, 96)]);
#pragma unroll
                for (int mt = 0; mt < MT; ++mt) {
                    union { unsigned short u[8]; bf16x8 v; } fa;
                    *reinterpret_cast<uint4*>(fa.u) =
                        *reinterpret_cast<const uint4*>(&s_w[swzo(mt * 16 + n, col, 96)]);
                    acc[mt][0] = __builtin_amdgcn_mfma_f32_16x16x32_bf16(fa.v, bf0.v, acc[mt][0], 0, 0, 0);
                    acc[mt][1] = __builtin_amdgcn_mfma_f32_16x16x32_bf16(fa.v, bf1.v, acc[mt][1], 0, 0, 0);
                }
            }
            if (os + 1 < OSPLIT || ks + 1 < KSPLIT)
                __syncthreads();
        }

        const int p0 = hw0 + pl0;
        const int p1 = hw0 + pl1;
        const size_t obase = (size_t)b * COUT * HW;
#pragma unroll
        for (int mt = 0; mt < MT; ++mt) {
#pragma unroll
            for (int nt = 0; nt < 2; ++nt) {
                const int p = (nt == 0) ? p0 : p1;
#pragma unroll
                for (int r = 0; r < 4; ++r) {
                    const int o = os * 96 + mt * 16 + q * 4 + r;
                    float v = acc[mt][nt][r] + s_b[o];
                    if constexpr (GELU) v = gelu_erf(v);
                    const size_t idx = obase + (size_t)o * HW + p;
                    if constexpr (HASRES) v += resid[idx];
                    if constexpr (__is_same(TOT, float)) out[idx] = v;
                    else                                 out[idx] = __float2bfloat16(v);
                }
            }
        }
    }
}

// ---------------- Fused FFN v3: out = x1 + ffn2(gelu(ffn1(x1))), x1 = x+proj(xa)
// v2 spilled: 20-VGPR float4 weight preload + full state > 128-reg cap at
// launch_bounds(512,4) -> 380 MB scratch traffic (WRITE 413 MB vs 98 expected).
// v3: pack-early WLOAD -- float4 transients die inside WLOAD, only 10 VGPRs
// (5x ushort4) cross the GEMM phase. Peak live ~105 regs < 128: no spill.
__global__ __launch_bounds__(512, 4) void ffn_fused(
    const bf16* __restrict__ xa, const float* __restrict__ x,
    const float* __restrict__ pw, const float* __restrict__ pb,
    const float* __restrict__ w1, const float* __restrict__ b1,
    const float* __restrict__ w2, const float* __restrict__ b2,
    float* __restrict__ out)
{
    __shared__ unsigned short s_w[96 * 96];     // 18,432 B  current W slice
    __shared__ unsigned short s_x1[128 * 96];   // 24,576 B  x1 bf16 (swz96)
    __shared__ unsigned short s_hx[128 * 96];   // 24,576 B  xa -> h0 -> h1
    __shared__ float          s_bias[384];      // pb[96] | b1[192] | b2[96]

    const int tid  = threadIdx.x;
    const int lane = tid & 63;
    const int w8   = tid >> 6;                  // wave 0..7
    const int q    = lane >> 4;
    const int n    = lane & 15;

    const int pos0 = blockIdx.x * 128;
    const int b    = pos0 >> 16;
    const int hw0  = pos0 & 65535;
    const int pl   = w8 * 16 + n;               // tile-local position
    const int p    = hw0 + pl;                  // global position

    // ---- weight slice preload, PACK-EARLY: only ushort4 wrp[5] (10 VGPRs)
    // survives past WLOAD; float4 transients die before the GEMM phase.
    ushort4 wrp[5];
    auto WLOAD = [&](const float* W, int row0, int col0, int rs) {
        float4 t[5];
#pragma unroll
        for (int i = 0; i < 5; ++i) {
            const int idx = tid + i * 512;
            if (i < 4 || tid < 256) {
                const int o = idx / 24, c4 = (idx - o * 24) * 4;
                t[i] = *reinterpret_cast<const float4*>(
                    &W[(size_t)(row0 + o) * rs + col0 + c4]);
            }
        }
#pragma unroll
        for (int i = 0; i < 5; ++i)
            if (i < 4 || tid < 256)
                wrp[i] = make_ushort4(f2bu(t[i].x), f2bu(t[i].y),
                                      f2bu(t[i].z), f2bu(t[i].w));
    };
    auto WWRITE = [&]() {
#pragma unroll
        for (int i = 0; i < 5; ++i) {
            const int idx = tid + i * 512;
            if (i < 4 || tid < 256) {
                const int o = idx / 24, c4 = (idx - o * 24) * 4;
                *reinterpret_cast<ushort4*>(&s_w[swzo(o, c4, 96)]) = wrp[i];
            }
        }
    };
    auto GEMM = [&](const unsigned short* B, f32x4 (&acc)[6]) {
#pragma unroll
        for (int kt = 0; kt < 3; ++kt) {
            const int col = kt * 32 + q * 8;
            union { unsigned short u[8]; bf16x8 v; } bf;
            *reinterpret_cast<uint4*>(bf.u) =
                *reinterpret_cast<const uint4*>(&B[swzo(pl, col, 96)]);
#pragma unroll
            for (int mt = 0; mt < 6; ++mt) {
                union { unsigned short u[8]; bf16x8 v; } fa;
                *reinterpret_cast<uint4*>(fa.u) =
                    *reinterpret_cast<const uint4*>(&s_w[swzo(mt * 16 + n, col, 96)]);
                acc[mt] = __builtin_amdgcn_mfma_f32_16x16x32_bf16(fa.v, bf.v, acc[mt], 0, 0, 0);
            }
        }
    };
    auto ST4 = [&](unsigned short* dst, int col4, float v0, float v1, float v2, float v3) {
        union { unsigned short u[4]; uint2 d; } t;
        t.u[0] = f2bu(v0); t.u[1] = f2bu(v1); t.u[2] = f2bu(v2); t.u[3] = f2bu(v3);
        *reinterpret_cast<uint2*>(&dst[swzo(pl, col4, 96)]) = t.d;  // col4%8 in {0,4}
    };

    // ---------- S0: xa -> s_hx (swz96), proj W -> s_w direct, biases
    {
        const bf16* inb = xa + (size_t)b * 96 * HW;
        for (int idx = tid; idx < 48 * 16; idx += 512) {
            const int cp = idx >> 4, pbk = idx & 15;
            const bf16* gp = inb + (size_t)(2 * cp) * HW + hw0 + pbk * 8;
            unsigned short ua[8], ub[8];
            *reinterpret_cast<uint4*>(ua) = *reinterpret_cast<const uint4*>(gp);
            *reinterpret_cast<uint4*>(ub) = *reinterpret_cast<const uint4*>(gp + HW);
#pragma unroll
            for (int i = 0; i < 8; ++i) {
                uint d = (uint)ua[i] | ((uint)ub[i] << 16);
                *reinterpret_cast<uint*>(&s_hx[swzo(pbk * 8 + i, 2 * cp, 96)]) = d;
            }
        }
        for (int k = tid; k < 96 * 24; k += 512) {
            const int o = k / 24, c4 = (k - o * 24) * 4;
            float4 w4 = *reinterpret_cast<const float4*>(&pw[(size_t)o * 96 + c4]);
            ushort4 pk = make_ushort4(f2bu(w4.x), f2bu(w4.y), f2bu(w4.z), f2bu(w4.w));
            *reinterpret_cast<ushort4*>(&s_w[swzo(o, c4, 96)]) = pk;
        }
        if (tid < 96)  s_bias[tid]       = pb[tid];
        if (tid < 192) s_bias[96 + tid]  = b1[tid];
        if (tid < 96)  s_bias[288 + tid] = b2[tid];
    }
    __syncthreads();

    // ---------- P1: proj GEMM (+ preload w1h0, + x resid loads)
    WLOAD(w1, 0, 0, 96);
    float xr[6][4];
    {
        const size_t xbase = (size_t)b * 96 * HW;
#pragma unroll
        for (int mt = 0; mt < 6; ++mt)
#pragma unroll
            for (int r = 0; r < 4; ++r)
                xr[mt][r] = x[xbase + (size_t)(mt * 16 + q * 4 + r) * HW + p];
    }
    float x1f[6][4];
    {
        f32x4 accp[6];
#pragma unroll
        for (int mt = 0; mt < 6; ++mt) accp[mt] = {0.f, 0.f, 0.f, 0.f};
        GEMM(s_hx, accp);
#pragma unroll
        for (int mt = 0; mt < 6; ++mt) {
#pragma unroll
            for (int r = 0; r < 4; ++r)
                x1f[mt][r] = accp[mt][r] + s_bias[mt * 16 + q * 4 + r] + xr[mt][r];
            ST4(s_x1, mt * 16 + q * 4, x1f[mt][0], x1f[mt][1], x1f[mt][2], x1f[mt][3]);
        }
    }
    __syncthreads();

    // ---------- P2: write w1h0
    WWRITE();
    __syncthreads();

    // ---------- P3: GEMM1 h0 (+ preload w2k0); h0 -> s_hx (xa dead)
    WLOAD(w2, 0, 0, 192);
    {
        f32x4 a1[6];
#pragma unroll
        for (int mt = 0; mt < 6; ++mt) a1[mt] = {0.f, 0.f, 0.f, 0.f};
        GEMM(s_x1, a1);
#pragma unroll
        for (int mt = 0; mt < 6; ++mt) {
            float v0 = gelu_erf(a1[mt][0] + s_bias[96 + mt * 16 + q * 4 + 0]);
            float v1 = gelu_erf(a1[mt][1] + s_bias[96 + mt * 16 + q * 4 + 1]);
            float v2 = gelu_erf(a1[mt][2] + s_bias[96 + mt * 16 + q * 4 + 2]);
            float v3 = gelu_erf(a1[mt][3] + s_bias[96 + mt * 16 + q * 4 + 3]);
            ST4(s_hx, mt * 16 + q * 4, v0, v1, v2, v3);
        }
    }
    __syncthreads();

    // ---------- P4: write w2k0
    WWRITE();
    __syncthreads();

    // ---------- P5: GEMM2 k0 (+ preload w1h1)
    f32x4 acc2[6];
#pragma unroll
    for (int mt = 0; mt < 6; ++mt) acc2[mt] = {0.f, 0.f, 0.f, 0.f};
    WLOAD(w1, 96, 0, 96);
    GEMM(s_hx, acc2);
    __syncthreads();

    // ---------- P6: write w1h1
    WWRITE();
    __syncthreads();

    // ---------- P7: GEMM1 h1 (+ preload w2k1); h1 -> s_hx (h0 dead)
    WLOAD(w2, 0, 96, 192);
    {
        f32x4 a1[6];
#pragma unroll
        for (int mt = 0; mt < 6; ++mt) a1[mt] = {0.f, 0.f, 0.f, 0.f};
        GEMM(s_x1, a1);
#pragma unroll
        for (int mt = 0; mt < 6; ++mt) {
            float v0 = gelu_erf(a1[mt][0] + s_bias[192 + mt * 16 + q * 4 + 0]);
            float v1 = gelu_erf(a1[mt][1] + s_bias[192 + mt * 16 + q * 4 + 1]);
            float v2 = gelu_erf(a1[mt][2] + s_bias[192 + mt * 16 + q * 4 + 2]);
            float v3 = gelu_erf(a1[mt][3] + s_bias[192 + mt * 16 + q * 4 + 3]);
            ST4(s_hx, mt * 16 + q * 4, v0, v1, v2, v3);
        }
    }
    __syncthreads();

    // ---------- P8: write w2k1
    WWRITE();
    __syncthreads();

    // ---------- P9: GEMM2 k1 + epilogue (out written exactly once)
    GEMM(s_hx, acc2);
    {
        const size_t obase = (size_t)b * 96 * HW;
#pragma unroll
        for (int mt = 0; mt < 6; ++mt)
#pragma unroll
            for (int r = 0; r < 4; ++r) {
                const int o = mt * 16 + q * 4 + r;
                out[obase + (size_t)o * HW + p] = x1f[mt][r] + acc2[mt][r] + s_bias[288 + o];
            }
    }
}

// ---------------- Kernel 3: experts, TRANSPOSED LDS stencil ----------------
#define XR     20
#define XPITCH 22      // 11 dwords (odd)
#define TPITCH 10      // 5 dwords (odd)
#define XCOLS  268
#define TCOLS  258

__global__ __launch_bounds__(256) void experts_kernel(
    const bf16* __restrict__ xn, const bf16* __restrict__ t0,
    const float* __restrict__ w0, const float* __restrict__ b0,
    const float* __restrict__ w1, const float* __restrict__ b1,
    const float* __restrict__ w2, const float* __restrict__ b2,
    const float* __restrict__ sw, const float* __restrict__ prompt,
    bf16* __restrict__ xa)
{
    __shared__ alignas(16) unsigned short sxT[XCOLS * XPITCH];
    __shared__ alignas(16) unsigned short stT[TCOLS * TPITCH];

    const int tid  = threadIdx.x;
    const int lane = tid & 63;
    const int wave = tid >> 6;
    const int bid = blockIdx.x;
    const int h0  = (bid & 31) * 8;
    const int bc  = bid >> 5;
    const int b   = bc / 96;
    const int c   = bc - b * 96;
    const size_t pbase = (size_t)bc * HW;

    const bf16* xp = xn + pbase;
    const bf16* tp = t0 + pbase;
    uint* sx32 = reinterpret_cast<uint*>(sxT);
    uint* st32 = reinterpret_cast<uint*>(stT);

    if (tid < 132) {
        int cc = tid / 11, d = tid - cc * 11;
        int col = (cc < 6) ? cc : 256 + cc;
        sx32[col * 11 + d] = 0u;
    } else if (tid < 142) {
        int i = tid - 132;
        int col = (i < 5) ? 0 : 257;
        int d   = (i < 5) ? i : i - 5;
        st32[col * 5 + d] = 0u;
    }

    {
        const int rp = (lane >> 2) & 7;
        const int ch = 8 * wave + (lane & 3) + ((lane >> 5) << 2);
        const int gh0 = h0 - 6 + 2 * rp, gh1 = gh0 + 1;
        union { uint4 q; unsigned short u[8]; } a, bb;
        a.q  = ((unsigned)gh0 < 256u) ? *reinterpret_cast<const uint4*>(xp + gh0 * WID + ch * 8)
                                      : make_uint4(0u, 0u, 0u, 0u);
        bb.q = ((unsigned)gh1 < 256u) ? *reinterpret_cast<const uint4*>(xp + gh1 * WID + ch * 8)
                                      : make_uint4(0u, 0u, 0u, 0u);
        const int base = 11 * (6 + 8 * ch) + rp;
#pragma unroll
        for (int j = 0; j < 8; ++j)
            sx32[base + 11 * j] = (uint)a.u[j] | ((uint)bb.u[j] << 16);
    }
    if (wave == 2) {
        const int rp = 8 + ((lane >> 2) & 1);
        const int ch = (lane & 3) + (((lane >> 3) & 7) << 2);
        const int gh0 = h0 - 6 + 2 * rp, gh1 = gh0 + 1;
        union { uint4 q; unsigned short u[8]; } a, bb;
        a.q  = ((unsigned)gh0 < 256u) ? *reinterpret_cast<const uint4*>(xp + gh0 * WID + ch * 8)
                                      : make_uint4(0u, 0u, 0u, 0u);
        bb.q = ((unsigned)gh1 < 256u) ? *reinterpret_cast<const uint4*>(xp + gh1 * WID + ch * 8)
                                      : make_uint4(0u, 0u, 0u, 0u);
        const int base = 11 * (6 + 8 * ch) + rp;
#pragma unroll
        for (int j = 0; j < 8; ++j)
            sx32[base + 11 * j] = (uint)a.u[j] | ((uint)bb.u[j] << 16);
    }
    if (wave < 2) {
        const int rp = (lane >> 3) & 3;
        const int ch = 16 * wave + (lane & 7) + ((lane >> 5) << 3);
        const int gh0 = h0 - 1 + 2 * rp, gh1 = gh0 + 1;
        union { uint4 q; unsigned short u[8]; } a, bb;
        a.q  = ((unsigned)gh0 < 256u) ? *reinterpret_cast<const uint4*>(tp + gh0 * WID + ch * 8)
                                      : make_uint4(0u, 0u, 0u, 0u);
        bb.q = ((unsigned)gh1 < 256u) ? *reinterpret_cast<const uint4*>(tp + gh1 * WID + ch * 8)
                                      : make_uint4(0u, 0u, 0u, 0u);
        const int base = 5 * (1 + 8 * ch) + rp;
#pragma unroll
        for (int j = 0; j < 8; ++j)
            st32[base + 5 * j] = (uint)a.u[j] | ((uint)bb.u[j] << 16);
    }
    if (wave == 3 && lane < 32) {
        const int rp = 4;
        const int ch = lane;
        const int gh0 = h0 - 1 + 2 * rp, gh1 = gh0 + 1;
        union { uint4 q; unsigned short u[8]; } a, bb;
        a.q  = ((unsigned)gh0 < 256u) ? *reinterpret_cast<const uint4*>(tp + gh0 * WID + ch * 8)
                                      : make_uint4(0u, 0u, 0u, 0u);
        bb.q = ((unsigned)gh1 < 256u) ? *reinterpret_cast<const uint4*>(tp + gh1 * WID + ch * 8)
                                      : make_uint4(0u, 0u, 0u, 0u);
        const int base = 5 * (1 + 8 * ch) + rp;
#pragma unroll
        for (int j = 0; j < 8; ++j)
            st32[base + 5 * j] = (uint)a.u[j] | ((uint)bb.u[j] << 16);
    }

    float wk0[9], wk1[9], wk2[25];
#pragma unroll
    for (int i = 0; i < 9; ++i)  wk0[i] = w0[c * 9 + i];
#pragma unroll
    for (int i = 0; i < 9; ++i)  wk1[i] = w1[c * 9 + i];
#pragma unroll
    for (int i = 0; i < 25; ++i) wk2[i] = w2[c * 25 + i];
    const float bb0 = b0[c], bb1 = b1[c], bb2 = b2[c];
    const float s0 = sw[b * 3 + 0], s1 = sw[b * 3 + 1], s2 = sw[b * 3 + 2];
    const float pr = 1.f + prompt[b * 96 + c];

    __syncthreads();

    const int w = tid;
    float acc0[8], acc1[8], acc2[8];
#pragma unroll
    for (int r = 0; r < 8; ++r) { acc0[r] = bb0; acc1[r] = bb1; acc2[r] = bb2; }

    const unsigned short* bx = &sxT[w * XPITCH];
    const unsigned short* bt = &stT[w * TPITCH];

#pragma unroll
    for (int kw = 0; kw < 5; ++kw) {
        float cv[20];
#pragma unroll
        for (int j = 0; j < 10; ++j) {
            unsigned u = *reinterpret_cast<const unsigned*>(&bx[kw * 3 * XPITCH + 2 * j]);
            cv[2 * j]     = lo2f(u);
            cv[2 * j + 1] = hi2f(u);
        }
#pragma unroll
        for (int kh = 0; kh < 5; ++kh) {
            const float wv = wk2[kh * 5 + kw];
#pragma unroll
            for (int r = 0; r < 8; ++r) acc2[r] += wv * cv[r + 3 * kh];
        }
        if (kw == 2) {
#pragma unroll
            for (int kh = 0; kh < 3; ++kh) {
                const float wv = wk1[kh * 3 + 1];
#pragma unroll
                for (int r = 0; r < 8; ++r) acc1[r] += wv * cv[r + 2 * kh + 4];
            }
        }
    }
#pragma unroll
    for (int kwh = 0; kwh < 2; ++kwh) {
        const int kw = kwh * 2;
        float cv[12];
#pragma unroll
        for (int j = 0; j < 6; ++j) {
            unsigned u = *reinterpret_cast<const unsigned*>(&bx[(4 + 2 * kw) * XPITCH + 4 + 2 * j]);
            cv[2 * j]     = lo2f(u);
            cv[2 * j + 1] = hi2f(u);
        }
#pragma unroll
        for (int kh = 0; kh < 3; ++kh) {
            const float wv = wk1[kh * 3 + kw];
#pragma unroll
            for (int r = 0; r < 8; ++r) acc1[r] += wv * cv[r + 2 * kh];
        }
    }
#pragma unroll
    for (int kw = 0; kw < 3; ++kw) {
        float cv[10];
#pragma unroll
        for (int j = 0; j < 5; ++j) {
            unsigned u = *reinterpret_cast<const unsigned*>(&bt[kw * TPITCH + 2 * j]);
            cv[2 * j]     = lo2f(u);
            cv[2 * j + 1] = hi2f(u);
        }
#pragma unroll
        for (int kh = 0; kh < 3; ++kh) {
            const float wv = wk0[kh * 3 + kw];
#pragma unroll
            for (int r = 0; r < 8; ++r) acc0[r] += wv * cv[r + kh];
        }
    }

    bf16* op = xa + pbase + (size_t)h0 * WID + w;
#pragma unroll
    for (int r = 0; r < 8; ++r) {
        float v = (s0 * acc0[r] + s1 * acc1[r] + s2 * acc2[r]) * pr;
        op[r * WID] = __float2bfloat16(v);
    }
}

// ---------------- launch ----------------
extern "C" void kernel_launch(void* const* d_in, const int* in_sizes, int n_in,
                              void* d_out, int out_size, void* d_ws, size_t ws_size,
                              hipStream_t stream)
{
    const float* x       = (const float*)d_in[0];
    const float* prompt  = (const float*)d_in[1];
    const float* sw      = (const float*)d_in[2];
    const float* ln_w    = (const float*)d_in[3];
    const float* ln_b    = (const float*)d_in[4];
    const float* e0_pw_w = (const float*)d_in[5];
    const float* e0_pw_b = (const float*)d_in[6];
    const float* e0_dw_w = (const float*)d_in[7];
    const float* e0_dw_b = (const float*)d_in[8];
    const float* e1_dw_w = (const float*)d_in[9];
    const float* e1_dw_b = (const float*)d_in[10];
    const float* e2_dw_w = (const float*)d_in[11];
    const float* e2_dw_b = (const float*)d_in[12];
    const float* proj_w  = (const float*)d_in[13];
    const float* proj_b  = (const float*)d_in[14];
    const float* ffn1_w  = (const float*)d_in[15];
    const float* ffn1_b  = (const float*)d_in[16];
    const float* ffn2_w  = (const float*)d_in[17];
    const float* ffn2_b  = (const float*)d_in[18];

    float* out = (float*)d_out;
    bf16*  ws  = (bf16*)d_ws;
    bf16*  A   = ws;                 // xn  bf16 (48 MB)
    bf16*  Bt  = ws + S_ELEMS;       // t0  bf16 (48 MB)
    bf16*  Cx  = ws + 2 * S_ELEMS;   // xa  bf16 (48 MB)

    // 1) xn = LayerNorm_c(x)
    ln_kernel<<<512, 256, 0, stream>>>(x, ln_w, ln_b, A);
    // 2) t0 = conv1x1(xn, e0_pw)
    conv1x1_mfma<bf16, bf16, 96, 96, false, false>
        <<<2048, 256, 0, stream>>>(A, e0_pw_w, e0_pw_b, nullptr, Bt);
    // 3) xa = (s0*dw3(t0) + s1*dw3d2(xn) + s2*dw5d3(xn)) * (1+prompt)
    experts_kernel<<<12288, 256, 0, stream>>>(A, Bt, e0_dw_w, e0_dw_b, e1_dw_w, e1_dw_b,
                                              e2_dw_w, e2_dw_b, sw, prompt, Cx);
    // 4) out = x1 + ffn2(gelu(ffn1(x1))), x1 = x + proj(xa)   [fused k4+k5+k6]
    ffn_fused<<<2048, 512, 0, stream>>>(Cx, x, proj_w, proj_b,
                                        ffn1_w, ffn1_b, ffn2_w, ffn2_b, out);
}

// Round 10
// 425.452 us; speedup vs baseline: 1.1645x; 1.0955x over previous
//
#include <hip/hip_runtime.h>
#include <hip/hip_bf16.h>

typedef __hip_bfloat16 bf16;
typedef __attribute__((ext_vector_type(8))) __bf16 bf16x8;
typedef __attribute__((ext_vector_type(4))) float  f32x4;

#define HW   65536
#define WID  256
#define CC   96
#define NB   4
static const size_t S_ELEMS = (size_t)NB * CC * HW;  // 25,165,824 elements

__device__ __forceinline__ float lo2f(unsigned u) { unsigned x = u << 16;        return __builtin_bit_cast(float, x); }
__device__ __forceinline__ float hi2f(unsigned u) { unsigned x = u & 0xffff0000u; return __builtin_bit_cast(float, x); }
__device__ __forceinline__ unsigned short f2bu(float f) {
    return __builtin_bit_cast(unsigned short, __float2bfloat16(f));
}

// exact-GELU via Abramowitz-Stegun 7.1.26 erf (|err| < 1.5e-7)
__device__ __forceinline__ float gelu_erf(float v) {
    float z  = fabsf(v) * 0.70710678118654752f;
    float t  = __builtin_amdgcn_rcpf(1.f + 0.3275911f * z);
    float poly = t * (0.254829592f + t * (-0.284496736f + t * (1.421413741f
               + t * (-1.453152027f + t * 1.061405429f))));
    float erfz = 1.f - poly * __expf(-z * z);
    float erfv = copysignf(erfz, v);
    return 0.5f * v * (1.f + erfv);
}

// ---------------- Kernel 1: LayerNorm over channel dim of NCHW ----------------
__global__ __launch_bounds__(256) void ln_kernel(
    const float* __restrict__ x, const float* __restrict__ lw,
    const float* __restrict__ lb, bf16* __restrict__ y)
{
    int t  = blockIdx.x * 256 + threadIdx.x;   // [0, 131072)
    int b  = t >> 15;
    int hw = (t & 32767) * 2;
    size_t base = (size_t)b * CC * HW + hw;

    float s0 = 0.f, s1 = 0.f, q0 = 0.f, q1 = 0.f;
    for (int c = 0; c < CC; ++c) {
        float2 v = *reinterpret_cast<const float2*>(&x[base + (size_t)c * HW]);
        s0 += v.x; s1 += v.y; q0 += v.x * v.x; q1 += v.y * v.y;
    }
    float mu0 = s0 * (1.f / 96.f), mu1 = s1 * (1.f / 96.f);
    float rs0 = rsqrtf(q0 * (1.f / 96.f) - mu0 * mu0 + 1e-6f);
    float rs1 = rsqrtf(q1 * (1.f / 96.f) - mu1 * mu1 + 1e-6f);

    for (int c = 0; c < CC; ++c) {
        float2 v = *reinterpret_cast<const float2*>(&x[base + (size_t)c * HW]);
        float g = lw[c], be = lb[c];
        bf16 o[2];
        o[0] = __float2bfloat16((v.x - mu0) * rs0 * g + be);
        o[1] = __float2bfloat16((v.y - mu1) * rs1 * g + be);
        *reinterpret_cast<uint*>(&y[base + (size_t)c * HW]) = *reinterpret_cast<uint*>(o);
    }
}

// ---------------- conv1x1 via MFMA 16x16x32 bf16 (k2 only) -------------------
__device__ __forceinline__ int swzo(int row, int col, int width) {
    return (row * width + col) ^ ((((row & 7) ^ ((row >> 3) & 7)) << 3));
}

template <typename TI, typename TOT, int CIN, int COUT, bool GELU, bool HASRES>
__global__ __launch_bounds__(256) void conv1x1_mfma(
    const TI* __restrict__ in, const float* __restrict__ wgt,
    const float* __restrict__ bias, const float* __restrict__ resid,
    TOT* __restrict__ out)
{
    constexpr int KSPLIT = CIN / 96;
    constexpr int OSPLIT = COUT / 96;
    constexpr int MT     = 6;
    static_assert(CIN == KSPLIT * 96 && COUT == OSPLIT * 96, "96-multiples only");

    __shared__ unsigned short s_w[96 * 96];
    __shared__ unsigned short s_x[128 * 96];
    __shared__ float          s_b[COUT];

    const int tid  = threadIdx.x;
    const int lane = tid & 63;
    const int wave = tid >> 6;
    const int q    = lane >> 4;
    const int n    = lane & 15;

    const int pos0 = blockIdx.x * 128;
    const int b    = pos0 >> 16;
    const int hw0  = pos0 & 65535;

    for (int k = tid; k < COUT; k += 256) s_b[k] = bias[k];

    const TI* inb = in + (size_t)b * CIN * HW;
    const int pl0 = wave * 32 + n;
    const int pl1 = pl0 + 16;

#pragma unroll
    for (int os = 0; os < OSPLIT; ++os) {
        f32x4 acc[MT][2];
#pragma unroll
        for (int mt = 0; mt < MT; ++mt) {
            acc[mt][0] = {0.f, 0.f, 0.f, 0.f};
            acc[mt][1] = {0.f, 0.f, 0.f, 0.f};
        }

#pragma unroll
        for (int ks = 0; ks < KSPLIT; ++ks) {
            for (int k = tid; k < 96 * 24; k += 256) {
                int o = k / 24, c4 = (k - o * 24) * 4;
                float4 w4 = *reinterpret_cast<const float4*>(
                    &wgt[(size_t)(os * 96 + o) * CIN + ks * 96 + c4]);
                ushort4 pk = make_ushort4(f2bu(w4.x), f2bu(w4.y), f2bu(w4.z), f2bu(w4.w));
                *reinterpret_cast<ushort4*>(&s_w[swzo(o, c4, 96)]) = pk;
            }
            if (KSPLIT > 1 || os == 0) {
                for (int idx = tid; idx < 48 * 16; idx += 256) {
                    const int cp = idx >> 4;
                    const int pb = idx & 15;
                    const TI* gp = inb + (size_t)(ks * 96 + 2 * cp) * HW + hw0 + pb * 8;
                    unsigned short ua[8], ub[8];
                    if constexpr (__is_same(TI, float)) {
                        float4 a0 = *reinterpret_cast<const float4*>(gp);
                        float4 a1 = *reinterpret_cast<const float4*>(gp + 4);
                        float4 b0 = *reinterpret_cast<const float4*>(gp + HW);
                        float4 b1 = *reinterpret_cast<const float4*>(gp + HW + 4);
                        ua[0]=f2bu(a0.x); ua[1]=f2bu(a0.y); ua[2]=f2bu(a0.z); ua[3]=f2bu(a0.w);
                        ua[4]=f2bu(a1.x); ua[5]=f2bu(a1.y); ua[6]=f2bu(a1.z); ua[7]=f2bu(a1.w);
                        ub[0]=f2bu(b0.x); ub[1]=f2bu(b0.y); ub[2]=f2bu(b0.z); ub[3]=f2bu(b0.w);
                        ub[4]=f2bu(b1.x); ub[5]=f2bu(b1.y); ub[6]=f2bu(b1.z); ub[7]=f2bu(b1.w);
                    } else {
                        *reinterpret_cast<uint4*>(ua) = *reinterpret_cast<const uint4*>(gp);
                        *reinterpret_cast<uint4*>(ub) = *reinterpret_cast<const uint4*>(gp + HW);
                    }
#pragma unroll
                    for (int i = 0; i < 8; ++i) {
                        uint d = (uint)ua[i] | ((uint)ub[i] << 16);
                        *reinterpret_cast<uint*>(&s_x[swzo(pb * 8 + i, 2 * cp, 96)]) = d;
                    }
                }
            }
            __syncthreads();

#pragma unroll
            for (int kt = 0; kt < 3; ++kt) {
                const int col = kt * 32 + q * 8;
                union { unsigned short u[8]; bf16x8 v; } bf0, bf1;
                *reinterpret_cast<uint4*>(bf0.u) =
                    *reinterpret_cast<const uint4*>(&s_x[swzo(pl0, col, 96)]);
                *reinterpret_cast<uint4*>(bf1.u) =
                    *reinterpret_cast<const uint4*>(&s_x[swzo(pl1, col, 96)]);
#pragma unroll
                for (int mt = 0; mt < MT; ++mt) {
                    union { unsigned short u[8]; bf16x8 v; } fa;
                    *reinterpret_cast<uint4*>(fa.u) =
                        *reinterpret_cast<const uint4*>(&s_w[swzo(mt * 16 + n, col, 96)]);
                    acc[mt][0] = __builtin_amdgcn_mfma_f32_16x16x32_bf16(fa.v, bf0.v, acc[mt][0], 0, 0, 0);
                    acc[mt][1] = __builtin_amdgcn_mfma_f32_16x16x32_bf16(fa.v, bf1.v, acc[mt][1], 0, 0, 0);
                }
            }
            if (os + 1 < OSPLIT || ks + 1 < KSPLIT)
                __syncthreads();
        }

        const int p0 = hw0 + pl0;
        const int p1 = hw0 + pl1;
        const size_t obase = (size_t)b * COUT * HW;
#pragma unroll
        for (int mt = 0; mt < MT; ++mt) {
#pragma unroll
            for (int nt = 0; nt < 2; ++nt) {
                const int p = (nt == 0) ? p0 : p1;
#pragma unroll
                for (int r = 0; r < 4; ++r) {
                    const int o = os * 96 + mt * 16 + q * 4 + r;
                    float v = acc[mt][nt][r] + s_b[o];
                    if constexpr (GELU) v = gelu_erf(v);
                    const size_t idx = obase + (size_t)o * HW + p;
                    if constexpr (HASRES) v += resid[idx];
                    if constexpr (__is_same(TOT, float)) out[idx] = v;
                    else                                 out[idx] = __float2bfloat16(v);
                }
            }
        }
    }
}

// ---------------- Fused FFN v4: out = x1 + ffn2(gelu(ffn1(x1))), x1 = x+proj(xa)
// v3 STILL spilled at launch_bounds(512,4): on gfx950's unified VGPR/AGPR file
// the MFMA accumulators claim an AGPR block (~64), and the 128-reg/wave cap
// left only 64 arch VGPRs -> 240 MB scratch writebacks (WRITE 336 vs 98 MB).
// v4 = v3 with launch_bounds(512,2): 256-reg cap, natural allocation ~105-130
// regs, no spill. If <=128 we keep 2 blocks/CU; even at 1 block the removed
// spill traffic (~80 us at 3 TB/s) dominates the occupancy loss.
__global__ __launch_bounds__(512, 2) void ffn_fused(
    const bf16* __restrict__ xa, const float* __restrict__ x,
    const float* __restrict__ pw, const float* __restrict__ pb,
    const float* __restrict__ w1, const float* __restrict__ b1,
    const float* __restrict__ w2, const float* __restrict__ b2,
    float* __restrict__ out)
{
    __shared__ unsigned short s_w[96 * 96];     // 18,432 B  current W slice
    __shared__ unsigned short s_x1[128 * 96];   // 24,576 B  x1 bf16 (swz96)
    __shared__ unsigned short s_hx[128 * 96];   // 24,576 B  xa -> h0 -> h1
    __shared__ float          s_bias[384];      // pb[96] | b1[192] | b2[96]

    const int tid  = threadIdx.x;
    const int lane = tid & 63;
    const int w8   = tid >> 6;                  // wave 0..7
    const int q    = lane >> 4;
    const int n    = lane & 15;

    const int pos0 = blockIdx.x * 128;
    const int b    = pos0 >> 16;
    const int hw0  = pos0 & 65535;
    const int pl   = w8 * 16 + n;               // tile-local position
    const int p    = hw0 + pl;                  // global position

    // ---- weight slice preload, PACK-EARLY: only ushort4 wrp[5] (10 VGPRs)
    // survives past WLOAD; float4 transients die before the GEMM phase.
    ushort4 wrp[5];
    auto WLOAD = [&](const float* W, int row0, int col0, int rs) {
        float4 t[5];
#pragma unroll
        for (int i = 0; i < 5; ++i) {
            const int idx = tid + i * 512;
            if (i < 4 || tid < 256) {
                const int o = idx / 24, c4 = (idx - o * 24) * 4;
                t[i] = *reinterpret_cast<const float4*>(
                    &W[(size_t)(row0 + o) * rs + col0 + c4]);
            }
        }
#pragma unroll
        for (int i = 0; i < 5; ++i)
            if (i < 4 || tid < 256)
                wrp[i] = make_ushort4(f2bu(t[i].x), f2bu(t[i].y),
                                      f2bu(t[i].z), f2bu(t[i].w));
    };
    auto WWRITE = [&]() {
#pragma unroll
        for (int i = 0; i < 5; ++i) {
            const int idx = tid + i * 512;
            if (i < 4 || tid < 256) {
                const int o = idx / 24, c4 = (idx - o * 24) * 4;
                *reinterpret_cast<ushort4*>(&s_w[swzo(o, c4, 96)]) = wrp[i];
            }
        }
    };
    auto GEMM = [&](const unsigned short* B, f32x4 (&acc)[6]) {
#pragma unroll
        for (int kt = 0; kt < 3; ++kt) {
            const int col = kt * 32 + q * 8;
            union { unsigned short u[8]; bf16x8 v; } bf;
            *reinterpret_cast<uint4*>(bf.u) =
                *reinterpret_cast<const uint4*>(&B[swzo(pl, col, 96)]);
#pragma unroll
            for (int mt = 0; mt < 6; ++mt) {
                union { unsigned short u[8]; bf16x8 v; } fa;
                *reinterpret_cast<uint4*>(fa.u) =
                    *reinterpret_cast<const uint4*>(&s_w[swzo(mt * 16 + n, col, 96)]);
                acc[mt] = __builtin_amdgcn_mfma_f32_16x16x32_bf16(fa.v, bf.v, acc[mt], 0, 0, 0);
            }
        }
    };
    auto ST4 = [&](unsigned short* dst, int col4, float v0, float v1, float v2, float v3) {
        union { unsigned short u[4]; uint2 d; } t;
        t.u[0] = f2bu(v0); t.u[1] = f2bu(v1); t.u[2] = f2bu(v2); t.u[3] = f2bu(v3);
        *reinterpret_cast<uint2*>(&dst[swzo(pl, col4, 96)]) = t.d;  // col4%8 in {0,4}
    };

    // ---------- S0: xa -> s_hx (swz96), proj W -> s_w direct, biases
    {
        const bf16* inb = xa + (size_t)b * 96 * HW;
        for (int idx = tid; idx < 48 * 16; idx += 512) {
            const int cp = idx >> 4, pbk = idx & 15;
            const bf16* gp = inb + (size_t)(2 * cp) * HW + hw0 + pbk * 8;
            unsigned short ua[8], ub[8];
            *reinterpret_cast<uint4*>(ua) = *reinterpret_cast<const uint4*>(gp);
            *reinterpret_cast<uint4*>(ub) = *reinterpret_cast<const uint4*>(gp + HW);
#pragma unroll
            for (int i = 0; i < 8; ++i) {
                uint d = (uint)ua[i] | ((uint)ub[i] << 16);
                *reinterpret_cast<uint*>(&s_hx[swzo(pbk * 8 + i, 2 * cp, 96)]) = d;
            }
        }
        for (int k = tid; k < 96 * 24; k += 512) {
            const int o = k / 24, c4 = (k - o * 24) * 4;
            float4 w4 = *reinterpret_cast<const float4*>(&pw[(size_t)o * 96 + c4]);
            ushort4 pk = make_ushort4(f2bu(w4.x), f2bu(w4.y), f2bu(w4.z), f2bu(w4.w));
            *reinterpret_cast<ushort4*>(&s_w[swzo(o, c4, 96)]) = pk;
        }
        if (tid < 96)  s_bias[tid]       = pb[tid];
        if (tid < 192) s_bias[96 + tid]  = b1[tid];
        if (tid < 96)  s_bias[288 + tid] = b2[tid];
    }
    __syncthreads();

    // ---------- P1: proj GEMM (+ preload w1h0, + x resid loads)
    WLOAD(w1, 0, 0, 96);
    float xr[6][4];
    {
        const size_t xbase = (size_t)b * 96 * HW;
#pragma unroll
        for (int mt = 0; mt < 6; ++mt)
#pragma unroll
            for (int r = 0; r < 4; ++r)
                xr[mt][r] = x[xbase + (size_t)(mt * 16 + q * 4 + r) * HW + p];
    }
    float x1f[6][4];
    {
        f32x4 accp[6];
#pragma unroll
        for (int mt = 0; mt < 6; ++mt) accp[mt] = {0.f, 0.f, 0.f, 0.f};
        GEMM(s_hx, accp);
#pragma unroll
        for (int mt = 0; mt < 6; ++mt) {
#pragma unroll
            for (int r = 0; r < 4; ++r)
                x1f[mt][r] = accp[mt][r] + s_bias[mt * 16 + q * 4 + r] + xr[mt][r];
            ST4(s_x1, mt * 16 + q * 4, x1f[mt][0], x1f[mt][1], x1f[mt][2], x1f[mt][3]);
        }
    }
    __syncthreads();

    // ---------- P2: write w1h0
    WWRITE();
    __syncthreads();

    // ---------- P3: GEMM1 h0 (+ preload w2k0); h0 -> s_hx (xa dead)
    WLOAD(w2, 0, 0, 192);
    {
        f32x4 a1[6];
#pragma unroll
        for (int mt = 0; mt < 6; ++mt) a1[mt] = {0.f, 0.f, 0.f, 0.f};
        GEMM(s_x1, a1);
#pragma unroll
        for (int mt = 0; mt < 6; ++mt) {
            float v0 = gelu_erf(a1[mt][0] + s_bias[96 + mt * 16 + q * 4 + 0]);
            float v1 = gelu_erf(a1[mt][1] + s_bias[96 + mt * 16 + q * 4 + 1]);
            float v2 = gelu_erf(a1[mt][2] + s_bias[96 + mt * 16 + q * 4 + 2]);
            float v3 = gelu_erf(a1[mt][3] + s_bias[96 + mt * 16 + q * 4 + 3]);
            ST4(s_hx, mt * 16 + q * 4, v0, v1, v2, v3);
        }
    }
    __syncthreads();

    // ---------- P4: write w2k0
    WWRITE();
    __syncthreads();

    // ---------- P5: GEMM2 k0 (+ preload w1h1)
    f32x4 acc2[6];
#pragma unroll
    for (int mt = 0; mt < 6; ++mt) acc2[mt] = {0.f, 0.f, 0.f, 0.f};
    WLOAD(w1, 96, 0, 96);
    GEMM(s_hx, acc2);
    __syncthreads();

    // ---------- P6: write w1h1
    WWRITE();
    __syncthreads();

    // ---------- P7: GEMM1 h1 (+ preload w2k1); h1 -> s_hx (h0 dead)
    WLOAD(w2, 0, 96, 192);
    {
        f32x4 a1[6];
#pragma unroll
        for (int mt = 0; mt < 6; ++mt) a1[mt] = {0.f, 0.f, 0.f, 0.f};
        GEMM(s_x1, a1);
#pragma unroll
        for (int mt = 0; mt < 6; ++mt) {
            float v0 = gelu_erf(a1[mt][0] + s_bias[192 + mt * 16 + q * 4 + 0]);
            float v1 = gelu_erf(a1[mt][1] + s_bias[192 + mt * 16 + q * 4 + 1]);
            float v2 = gelu_erf(a1[mt][2] + s_bias[192 + mt * 16 + q * 4 + 2]);
            float v3 = gelu_erf(a1[mt][3] + s_bias[192 + mt * 16 + q * 4 + 3]);
            ST4(s_hx, mt * 16 + q * 4, v0, v1, v2, v3);
        }
    }
    __syncthreads();

    // ---------- P8: write w2k1
    WWRITE();
    __syncthreads();

    // ---------- P9: GEMM2 k1 + epilogue (out written exactly once)
    GEMM(s_hx, acc2);
    {
        const size_t obase = (size_t)b * 96 * HW;
#pragma unroll
        for (int mt = 0; mt < 6; ++mt)
#pragma unroll
            for (int r = 0; r < 4; ++r) {
                const int o = mt * 16 + q * 4 + r;
                out[obase + (size_t)o * HW + p] = x1f[mt][r] + acc2[mt][r] + s_bias[288 + o];
            }
    }
}

// ---------------- Kernel 3: experts, TRANSPOSED LDS stencil ----------------
#define XR     20
#define XPITCH 22      // 11 dwords (odd)
#define TPITCH 10      // 5 dwords (odd)
#define XCOLS  268
#define TCOLS  258

__global__ __launch_bounds__(256) void experts_kernel(
    const bf16* __restrict__ xn, const bf16* __restrict__ t0,
    const float* __restrict__ w0, const float* __restrict__ b0,
    const float* __restrict__ w1, const float* __restrict__ b1,
    const float* __restrict__ w2, const float* __restrict__ b2,
    const float* __restrict__ sw, const float* __restrict__ prompt,
    bf16* __restrict__ xa)
{
    __shared__ alignas(16) unsigned short sxT[XCOLS * XPITCH];
    __shared__ alignas(16) unsigned short stT[TCOLS * TPITCH];

    const int tid  = threadIdx.x;
    const int lane = tid & 63;
    const int wave = tid >> 6;
    const int bid = blockIdx.x;
    const int h0  = (bid & 31) * 8;
    const int bc  = bid >> 5;
    const int b   = bc / 96;
    const int c   = bc - b * 96;
    const size_t pbase = (size_t)bc * HW;

    const bf16* xp = xn + pbase;
    const bf16* tp = t0 + pbase;
    uint* sx32 = reinterpret_cast<uint*>(sxT);
    uint* st32 = reinterpret_cast<uint*>(stT);

    if (tid < 132) {
        int cc = tid / 11, d = tid - cc * 11;
        int col = (cc < 6) ? cc : 256 + cc;
        sx32[col * 11 + d] = 0u;
    } else if (tid < 142) {
        int i = tid - 132;
        int col = (i < 5) ? 0 : 257;
        int d   = (i < 5) ? i : i - 5;
        st32[col * 5 + d] = 0u;
    }

    {
        const int rp = (lane >> 2) & 7;
        const int ch = 8 * wave + (lane & 3) + ((lane >> 5) << 2);
        const int gh0 = h0 - 6 + 2 * rp, gh1 = gh0 + 1;
        union { uint4 q; unsigned short u[8]; } a, bb;
        a.q  = ((unsigned)gh0 < 256u) ? *reinterpret_cast<const uint4*>(xp + gh0 * WID + ch * 8)
                                      : make_uint4(0u, 0u, 0u, 0u);
        bb.q = ((unsigned)gh1 < 256u) ? *reinterpret_cast<const uint4*>(xp + gh1 * WID + ch * 8)
                                      : make_uint4(0u, 0u, 0u, 0u);
        const int base = 11 * (6 + 8 * ch) + rp;
#pragma unroll
        for (int j = 0; j < 8; ++j)
            sx32[base + 11 * j] = (uint)a.u[j] | ((uint)bb.u[j] << 16);
    }
    if (wave == 2) {
        const int rp = 8 + ((lane >> 2) & 1);
        const int ch = (lane & 3) + (((lane >> 3) & 7) << 2);
        const int gh0 = h0 - 6 + 2 * rp, gh1 = gh0 + 1;
        union { uint4 q; unsigned short u[8]; } a, bb;
        a.q  = ((unsigned)gh0 < 256u) ? *reinterpret_cast<const uint4*>(xp + gh0 * WID + ch * 8)
                                      : make_uint4(0u, 0u, 0u, 0u);
        bb.q = ((unsigned)gh1 < 256u) ? *reinterpret_cast<const uint4*>(xp + gh1 * WID + ch * 8)
                                      : make_uint4(0u, 0u, 0u, 0u);
        const int base = 11 * (6 + 8 * ch) + rp;
#pragma unroll
        for (int j = 0; j < 8; ++j)
            sx32[base + 11 * j] = (uint)a.u[j] | ((uint)bb.u[j] << 16);
    }
    if (wave < 2) {
        const int rp = (lane >> 3) & 3;
        const int ch = 16 * wave + (lane & 7) + ((lane >> 5) << 3);
        const int gh0 = h0 - 1 + 2 * rp, gh1 = gh0 + 1;
        union { uint4 q; unsigned short u[8]; } a, bb;
        a.q  = ((unsigned)gh0 < 256u) ? *reinterpret_cast<const uint4*>(tp + gh0 * WID + ch * 8)
                                      : make_uint4(0u, 0u, 0u, 0u);
        bb.q = ((unsigned)gh1 < 256u) ? *reinterpret_cast<const uint4*>(tp + gh1 * WID + ch * 8)
                                      : make_uint4(0u, 0u, 0u, 0u);
        const int base = 5 * (1 + 8 * ch) + rp;
#pragma unroll
        for (int j = 0; j < 8; ++j)
            st32[base + 5 * j] = (uint)a.u[j] | ((uint)bb.u[j] << 16);
    }
    if (wave == 3 && lane < 32) {
        const int rp = 4;
        const int ch = lane;
        const int gh0 = h0 - 1 + 2 * rp, gh1 = gh0 + 1;
        union { uint4 q; unsigned short u[8]; } a, bb;
        a.q  = ((unsigned)gh0 < 256u) ? *reinterpret_cast<const uint4*>(tp + gh0 * WID + ch * 8)
                                      : make_uint4(0u, 0u, 0u, 0u);
        bb.q = ((unsigned)gh1 < 256u) ? *reinterpret_cast<const uint4*>(tp + gh1 * WID + ch * 8)
                                      : make_uint4(0u, 0u, 0u, 0u);
        const int base = 5 * (1 + 8 * ch) + rp;
#pragma unroll
        for (int j = 0; j < 8; ++j)
            st32[base + 5 * j] = (uint)a.u[j] | ((uint)bb.u[j] << 16);
    }

    float wk0[9], wk1[9], wk2[25];
#pragma unroll
    for (int i = 0; i < 9; ++i)  wk0[i] = w0[c * 9 + i];
#pragma unroll
    for (int i = 0; i < 9; ++i)  wk1[i] = w1[c * 9 + i];
#pragma unroll
    for (int i = 0; i < 25; ++i) wk2[i] = w2[c * 25 + i];
    const float bb0 = b0[c], bb1 = b1[c], bb2 = b2[c];
    const float s0 = sw[b * 3 + 0], s1 = sw[b * 3 + 1], s2 = sw[b * 3 + 2];
    const float pr = 1.f + prompt[b * 96 + c];

    __syncthreads();

    const int w = tid;
    float acc0[8], acc1[8], acc2[8];
#pragma unroll
    for (int r = 0; r < 8; ++r) { acc0[r] = bb0; acc1[r] = bb1; acc2[r] = bb2; }

    const unsigned short* bx = &sxT[w * XPITCH];
    const unsigned short* bt = &stT[w * TPITCH];

#pragma unroll
    for (int kw = 0; kw < 5; ++kw) {
        float cv[20];
#pragma unroll
        for (int j = 0; j < 10; ++j) {
            unsigned u = *reinterpret_cast<const unsigned*>(&bx[kw * 3 * XPITCH + 2 * j]);
            cv[2 * j]     = lo2f(u);
            cv[2 * j + 1] = hi2f(u);
        }
#pragma unroll
        for (int kh = 0; kh < 5; ++kh) {
            const float wv = wk2[kh * 5 + kw];
#pragma unroll
            for (int r = 0; r < 8; ++r) acc2[r] += wv * cv[r + 3 * kh];
        }
        if (kw == 2) {
#pragma unroll
            for (int kh = 0; kh < 3; ++kh) {
                const float wv = wk1[kh * 3 + 1];
#pragma unroll
                for (int r = 0; r < 8; ++r) acc1[r] += wv * cv[r + 2 * kh + 4];
            }
        }
    }
#pragma unroll
    for (int kwh = 0; kwh < 2; ++kwh) {
        const int kw = kwh * 2;
        float cv[12];
#pragma unroll
        for (int j = 0; j < 6; ++j) {
            unsigned u = *reinterpret_cast<const unsigned*>(&bx[(4 + 2 * kw) * XPITCH + 4 + 2 * j]);
            cv[2 * j]     = lo2f(u);
            cv[2 * j + 1] = hi2f(u);
        }
#pragma unroll
        for (int kh = 0; kh < 3; ++kh) {
            const float wv = wk1[kh * 3 + kw];
#pragma unroll
            for (int r = 0; r < 8; ++r) acc1[r] += wv * cv[r + 2 * kh];
        }
    }
#pragma unroll
    for (int kw = 0; kw < 3; ++kw) {
        float cv[10];
#pragma unroll
        for (int j = 0; j < 5; ++j) {
            unsigned u = *reinterpret_cast<const unsigned*>(&bt[kw * TPITCH + 2 * j]);
            cv[2 * j]     = lo2f(u);
            cv[2 * j + 1] = hi2f(u);
        }
#pragma unroll
        for (int kh = 0; kh < 3; ++kh) {
            const float wv = wk0[kh * 3 + kw];
#pragma unroll
            for (int r = 0; r < 8; ++r) acc0[r] += wv * cv[r + kh];
        }
    }

    bf16* op = xa + pbase + (size_t)h0 * WID + w;
#pragma unroll
    for (int r = 0; r < 8; ++r) {
        float v = (s0 * acc0[r] + s1 * acc1[r] + s2 * acc2[r]) * pr;
        op[r * WID] = __float2bfloat16(v);
    }
}

// ---------------- launch ----------------
extern "C" void kernel_launch(void* const* d_in, const int* in_sizes, int n_in,
                              void* d_out, int out_size, void* d_ws, size_t ws_size,
                              hipStream_t stream)
{
    const float* x       = (const float*)d_in[0];
    const float* prompt  = (const float*)d_in[1];
    const float* sw      = (const float*)d_in[2];
    const float* ln_w    = (const float*)d_in[3];
    const float* ln_b    = (const float*)d_in[4];
    const float* e0_pw_w = (const float*)d_in[5];
    const float* e0_pw_b = (const float*)d_in[6];
    const float* e0_dw_w = (const float*)d_in[7];
    const float* e0_dw_b = (const float*)d_in[8];
    const float* e1_dw_w = (const float*)d_in[9];
    const float* e1_dw_b = (const float*)d_in[10];
    const float* e2_dw_w = (const float*)d_in[11];
    const float* e2_dw_b = (const float*)d_in[12];
    const float* proj_w  = (const float*)d_in[13];
    const float* proj_b  = (const float*)d_in[14];
    const float* ffn1_w  = (const float*)d_in[15];
    const float* ffn1_b  = (const float*)d_in[16];
    const float* ffn2_w  = (const float*)d_in[17];
    const float* ffn2_b  = (const float*)d_in[18];

    float* out = (float*)d_out;
    bf16*  ws  = (bf16*)d_ws;
    bf16*  A   = ws;                 // xn  bf16 (48 MB)
    bf16*  Bt  = ws + S_ELEMS;       // t0  bf16 (48 MB)
    bf16*  Cx  = ws + 2 * S_ELEMS;   // xa  bf16 (48 MB)

    // 1) xn = LayerNorm_c(x)
    ln_kernel<<<512, 256, 0, stream>>>(x, ln_w, ln_b, A);
    // 2) t0 = conv1x1(xn, e0_pw)
    conv1x1_mfma<bf16, bf16, 96, 96, false, false>
        <<<2048, 256, 0, stream>>>(A, e0_pw_w, e0_pw_b, nullptr, Bt);
    // 3) xa = (s0*dw3(t0) + s1*dw3d2(xn) + s2*dw5d3(xn)) * (1+prompt)
    experts_kernel<<<12288, 256, 0, stream>>>(A, Bt, e0_dw_w, e0_dw_b, e1_dw_w, e1_dw_b,
                                              e2_dw_w, e2_dw_b, sw, prompt, Cx);
    // 4) out = x1 + ffn2(gelu(ffn1(x1))), x1 = x + proj(xa)   [fused k4+k5+k6]
    ffn_fused<<<2048, 512, 0, stream>>>(Cx, x, proj_w, proj_b,
                                        ffn1_w, ffn1_b, ffn2_w, ffn2_b, out);
}